// Round 4
// baseline (302.977 us; speedup 1.0000x reference)
//
#include <hip/hip_runtime.h>
#include <hip/hip_bf16.h>

// GCN link-prediction: 2x GCNConv(128->128) + edge dot scoring.
// Round 16: front-end restructure. gemm1 converts W1 f32->bf16 during LDS
// staging (64KB L2-hot, bitwise-identical results) so it no longer depends
// on the wt1-conversion blocks -> {gemm1 || pass1 || w2bf(wt2)} fuse into
// ONE launch (1091 blocks, co-resident at 5 blk/CU); only pass2 (~6us)
// remains serial on the CSR path. Aggregate inner loop reordered: shuffle
// src -> ISSUE 16 Hb gathers -> then shuffle dinv (R15's dependent dinv
// load had its wait blocking gather issue; now it hides under them).
// LESSONS BANKED:
// - aggregate gather: pinned at ~3.65 TB/s random-64B fabric floor.
// - never fuse latency-bound gather with reg/LDS-heavy MFMA (R10).
// - never read MFMA B-frags strided from global (R11).
// - random 8B scatter = 8x write amplification; atomics+scatter are
//   fabric-THROUGHPUT-bound, overlap doesn't help (R13).
// - CSR via 2-pass LDS counting sort >> 1M global atomics (R14: -57us).
// - dependent gather in meta path must not precede bulk-gather issue (R15).

#define N_NODES 100000
#define N_EDGES 1000000
#define N_LABEL 200000
#define D_FEAT 128
#define BM 128

#define NB 782        // coarse buckets: ceil(100000/128) nodes each
#define BCAP 2048     // temp capacity per bucket (mean 1279, +6sigma ~1500)
#define P1_EPT 16     // pass1 edges per thread
#define P1_BLOCKS 245 // ceil(1e6/4096)
#define G_GEMM 782    // ceil(100000/128)
#define G_W2BF 64     // 16384/256 (wt2 only)

typedef short bf16x8 __attribute__((ext_vector_type(8)));
typedef float f32x4 __attribute__((ext_vector_type(4)));

// ---- bf16 helpers (RNE) ----
__device__ inline unsigned int f2bf(float x) {
    unsigned int u = __float_as_uint(x);
    return (u + 0x7FFFu + ((u >> 16) & 1u)) >> 16;
}
__device__ inline unsigned int bf16pack(float a, float b) {
    return f2bf(a) | (f2bf(b) << 16);
}
__device__ inline float bflo(unsigned int u) { return __uint_as_float(u << 16); }
__device__ inline float bfhi(unsigned int u) { return __uint_as_float(u & 0xFFFF0000u); }

// ---------------- MFMA GEMM body, LDS-staged bf16 W ----------------
// F32W: stage W directly from f32 [k][n] (transposing+converting; W is 64KB
// L2-hot so the strided reads cost ~no HBM). Else stage pre-converted bf16
// Wt [n][k] via coalesced 16B chunks. Both use chunk-XOR swizzle.
template <bool BF16_IN, bool F32W>
__device__ __forceinline__ void gemm_body(const void* __restrict__ Xv,
                                          const void* __restrict__ Wsrc,
                                          unsigned int* __restrict__ Y,
                                          int nrows, int bid, short* Ws) {
    int t = threadIdx.x;
#pragma unroll
    for (int i = 0; i < 8; ++i) {
        int c = i * 256 + t;
        int n = c >> 4, q = c & 15;
        if constexpr (F32W) {
            const float* Wf = (const float*)Wsrc;  // [k][n]
            union { uint4 u; bf16x8 v; } cv;
            float f0 = Wf[(q * 8 + 0) * 128 + n];
            float f1 = Wf[(q * 8 + 1) * 128 + n];
            float f2 = Wf[(q * 8 + 2) * 128 + n];
            float f3 = Wf[(q * 8 + 3) * 128 + n];
            float f4 = Wf[(q * 8 + 4) * 128 + n];
            float f5 = Wf[(q * 8 + 5) * 128 + n];
            float f6 = Wf[(q * 8 + 6) * 128 + n];
            float f7 = Wf[(q * 8 + 7) * 128 + n];
            cv.u.x = bf16pack(f0, f1);
            cv.u.y = bf16pack(f2, f3);
            cv.u.z = bf16pack(f4, f5);
            cv.u.w = bf16pack(f6, f7);
            *(uint4*)&Ws[n * 128 + ((q ^ (n & 15)) << 3)] = cv.u;
        } else {
            const unsigned short* Wt = (const unsigned short*)Wsrc;  // [n][k]
            uint4 v = *(const uint4*)&Wt[(size_t)n * 128 + q * 8];
            *(uint4*)&Ws[n * 128 + ((q ^ (n & 15)) << 3)] = v;
        }
    }
    __syncthreads();

    int wv = t >> 6;
    int lane = t & 63, l16 = lane & 15, quad = lane >> 4;
    int rbase = bid * BM + wv * 32;

    f32x4 acc[2][8];
#pragma unroll
    for (int rt = 0; rt < 2; ++rt)
#pragma unroll
        for (int nt = 0; nt < 8; ++nt) acc[rt][nt] = (f32x4){0.f, 0.f, 0.f, 0.f};

#pragma unroll
    for (int kb = 0; kb < 4; ++kb) {
        bf16x8 af[2];
#pragma unroll
        for (int rt = 0; rt < 2; ++rt) {
            int row = rbase + rt * 16 + l16;
            if (row > nrows - 1) row = nrows - 1;
            if constexpr (BF16_IN) {
                const unsigned int* Xb = (const unsigned int*)Xv;
                af[rt] = *(const bf16x8*)&Xb[(size_t)row * 64 + kb * 16 + quad * 4];
            } else {
                const float* X = (const float*)Xv;
                float4 fa = ((const float4*)X)[(size_t)row * 32 + kb * 8 + quad * 2];
                float4 fb = ((const float4*)X)[(size_t)row * 32 + kb * 8 + quad * 2 + 1];
                union { uint4 u; bf16x8 v; } cv;
                cv.u.x = bf16pack(fa.x, fa.y);
                cv.u.y = bf16pack(fa.z, fa.w);
                cv.u.z = bf16pack(fb.x, fb.y);
                cv.u.w = bf16pack(fb.z, fb.w);
                af[rt] = cv.v;
            }
        }
        bf16x8 bfr[8];
#pragma unroll
        for (int nt = 0; nt < 8; ++nt) {
            int n = nt * 16 + l16;
            bfr[nt] = *(const bf16x8*)&Ws[n * 128 + (((kb * 4 + quad) ^ l16) << 3)];
        }
#pragma unroll
        for (int rt = 0; rt < 2; ++rt)
#pragma unroll
            for (int nt = 0; nt < 8; ++nt)
                acc[rt][nt] = __builtin_amdgcn_mfma_f32_16x16x32_bf16(
                    af[rt], bfr[nt], acc[rt][nt], 0, 0, 0);
    }

    short* Ys = (short*)Y;
#pragma unroll
    for (int rt = 0; rt < 2; ++rt)
#pragma unroll
        for (int reg = 0; reg < 4; ++reg) {
            int row = rbase + rt * 16 + quad * 4 + reg;
            if (row < nrows) {
#pragma unroll
                for (int nt = 0; nt < 8; ++nt)
                    Ys[(size_t)row * 128 + nt * 16 + l16] = (short)f2bf(acc[rt][nt][reg]);
            }
        }
}

// ---------------- fused front: gemm1 (f32 W) || pass1 || w2bf(wt2) ---------
// All three independent. 1091 blocks co-resident (5 blk/CU at 32KB LDS).
__global__ __launch_bounds__(256) void fused_front(
    const float* __restrict__ feat, const float* __restrict__ W1,
    unsigned int* __restrict__ Hb,
    const int* __restrict__ src, const int* __restrict__ dst,
    int* __restrict__ gcur, unsigned int* __restrict__ temp,
    const float* __restrict__ W2, unsigned short* __restrict__ wt2) {
    __shared__ __align__(16) short Ws[128 * 128];  // gemm tile / pass1 union
    int b = blockIdx.x, t = threadIdx.x;
    if (b < G_GEMM) {
        gemm_body<false, true>(feat, W1, Hb, N_NODES, b, Ws);
        return;
    }
    b -= G_GEMM;
    if (b >= P1_BLOCKS) {
        int i = (b - P1_BLOCKS) * 256 + t;  // 0..16383
        int n = i >> 7, k = i & 127;
        wt2[i] = (unsigned short)f2bf(W2[(size_t)k * 128 + n]);
        return;
    }
    // pass1: coarse bucket by dst>>7
    int* hist = (int*)Ws;      // NB ints
    int* base = hist + NB;     // NB ints
    for (int i = t; i < NB; i += 256) hist[i] = 0;
    __syncthreads();

    int se[P1_EPT], de[P1_EPT], rk[P1_EPT];
    int e0 = b * (P1_EPT * 256) + t;
#pragma unroll
    for (int j = 0; j < P1_EPT; ++j) {
        int e = e0 + j * 256;
        if (e < N_EDGES) {
            se[j] = src[e];
            de[j] = dst[e];
            rk[j] = atomicAdd(&hist[de[j] >> 7], 1);
        }
    }
    __syncthreads();
    for (int i = t; i < NB; i += 256) {
        int h = hist[i];
        base[i] = h ? atomicAdd(&gcur[i], h) : 0;
    }
    __syncthreads();
#pragma unroll
    for (int j = 0; j < P1_EPT; ++j) {
        int e = e0 + j * 256;
        if (e < N_EDGES) {
            int k = de[j] >> 7;
            int pos = base[k] + rk[j];
            if (pos < BCAP)
                temp[(size_t)k * BCAP + pos] =
                    (unsigned int)(((de[j] & 127) << 17) | se[j]);
        }
    }
}

// ---------------- pass 2: per-bucket LDS fine counting sort -----------------
__global__ __launch_bounds__(256) void pass2_sort(
    const int* __restrict__ gcur, const unsigned int* __restrict__ temp,
    int* __restrict__ row_ptr, float* __restrict__ dinv,
    int* __restrict__ packed) {
    int k = blockIdx.x, t = threadIdx.x;
    __shared__ unsigned int ed[BCAP];
    __shared__ int hist[128], rp[128], cur[128], sc[128];
    __shared__ int red[256];

    // gbase = sum of gcur[j] for j<k (gcur tiny, L2-hot)
    int part = 0;
    for (int j = t; j < NB; j += 256)
        if (j < k) part += gcur[j];
    red[t] = part;
    __syncthreads();
    for (int off = 128; off > 0; off >>= 1) {
        if (t < off) red[t] += red[t + off];
        __syncthreads();
    }
    int gbase = red[0];
    int nk = gcur[k];
    if (nk > BCAP) nk = BCAP;

    if (t < 128) { hist[t] = 0; cur[t] = 0; }
    __syncthreads();
    for (int i = t; i < nk; i += 256) {
        unsigned int v = temp[(size_t)k * BCAP + i];
        ed[i] = v;
        atomicAdd(&hist[v >> 17], 1);
    }
    __syncthreads();

    // exclusive scan over 128 bins
    if (t < 128) sc[t] = hist[t];
    __syncthreads();
    for (int off = 1; off < 128; off <<= 1) {
        int a = (t < 128 && t >= off) ? sc[t - off] : 0;
        __syncthreads();
        if (t < 128) sc[t] += a;
        __syncthreads();
    }
    if (t < 128) {
        rp[t] = sc[t] - hist[t];
        int n = k * 128 + t;
        if (n < N_NODES) {
            row_ptr[n] = gbase + rp[t];
            dinv[n] = rsqrtf((float)(hist[t] + 1));  // +1 self-loop
        }
    }
    if (k == NB - 1 && t == 0) row_ptr[N_NODES] = N_EDGES;
    __syncthreads();

    for (int i = t; i < nk; i += 256) {
        unsigned int v = ed[i];
        int dl = v >> 17;
        int r = atomicAdd(&cur[dl], 1);
        packed[gbase + rp[dl] + r] = (int)(v & 0x1FFFF);
    }
}

// standalone GEMM (layer 2, bf16 input, pre-converted wt2)
__global__ __launch_bounds__(256) void gemm128_mfma_bf16(const unsigned int* __restrict__ Xb,
                                                         const unsigned short* __restrict__ Wt,
                                                         unsigned int* __restrict__ Y,
                                                         int nrows) {
    __shared__ __align__(16) short Ws[128 * 128];
    gemm_body<true, false>(Xb, Wt, Y, nrows, blockIdx.x, Ws);
}

// ---------------- gather-aggregate: 2 nodes/wave, 16 gathers in flight ----
// packed = src only (4B/edge). x[v] = dv*(dv*H[v] + sum_s dinv[s]*H[s]) + b.
// Order per chunk: shuffle src -> ISSUE 16 row gathers -> shuffle dinv -> FMA
// (dinv's dependent-load latency hides under the row gathers).
template <bool RELU>
__global__ __launch_bounds__(256) void aggregate(const unsigned int* __restrict__ Hb,
                                                 const int* __restrict__ packed,
                                                 const int* __restrict__ row_ptr,
                                                 const float* __restrict__ dinv,
                                                 const float* __restrict__ bias,
                                                 unsigned int* __restrict__ Xb) {
    int v0 = blockIdx.x * 8 + (threadIdx.x >> 6) * 2;
    int v1 = v0 + 1;
    int lane = threadIdx.x & 63;
    if (v0 >= N_NODES) return;
    bool h1 = (v1 < N_NODES);

    int st0 = row_ptr[v0], en0 = row_ptr[v0 + 1];
    int st1 = h1 ? row_ptr[v1] : 0, en1 = h1 ? row_ptr[v1 + 1] : 0;
    float dv0 = dinv[v0];
    float dv1 = h1 ? dinv[v1] : 0.f;

    unsigned int su0 = Hb[(size_t)v0 * 64 + lane];
    float a0 = dv0 * bflo(su0), a1 = dv0 * bfhi(su0);
    unsigned int su1 = h1 ? Hb[(size_t)v1 * 64 + lane] : 0u;
    float b0 = dv1 * bflo(su1), b1 = dv1 * bfhi(su1);

    for (int c0 = st0, c1 = st1; c0 < en0 || c1 < en1; c0 += 32, c1 += 32) {
        int n0 = en0 - c0; n0 = n0 < 0 ? 0 : (n0 > 32 ? 32 : n0);
        int n1 = en1 - c1; n1 = n1 < 0 ? 0 : (n1 > 32 ? 32 : n1);
        int p = 0;
        float d = 0.f;
        if (lane < 32) {
            if (lane < n0) { p = packed[c0 + lane]; d = dinv[p]; }
        } else {
            if (lane - 32 < n1) { p = packed[c1 + lane - 32]; d = dinv[p]; }
        }
        int nmax = n0 > n1 ? n0 : n1;
        for (int j = 0; j < nmax; j += 8) {
            int sA[8], sB[8];
#pragma unroll
            for (int q = 0; q < 8; ++q) {
                sA[q] = __shfl(p, j + q);
                sB[q] = __shfl(p, 32 + j + q);
            }
            unsigned int uA[8], uB[8];
#pragma unroll
            for (int q = 0; q < 8; ++q) {
                uA[q] = Hb[(size_t)sA[q] * 64 + lane];
                uB[q] = Hb[(size_t)sB[q] * 64 + lane];
            }
            float dA[8], dB[8];
#pragma unroll
            for (int q = 0; q < 8; ++q) {
                dA[q] = __shfl(d, j + q);
                dB[q] = __shfl(d, 32 + j + q);
            }
#pragma unroll
            for (int q = 0; q < 8; ++q) {
                a0 = fmaf(dA[q], bflo(uA[q]), a0);
                a1 = fmaf(dA[q], bfhi(uA[q]), a1);
                b0 = fmaf(dB[q], bflo(uB[q]), b0);
                b1 = fmaf(dB[q], bfhi(uB[q]), b1);
            }
        }
    }

    float2 bb = ((const float2*)bias)[lane];
    a0 = fmaf(a0, dv0, bb.x);
    a1 = fmaf(a1, dv0, bb.y);
    b0 = fmaf(b0, dv1, bb.x);
    b1 = fmaf(b1, dv1, bb.y);
    if (RELU) {
        a0 = fmaxf(a0, 0.f);
        a1 = fmaxf(a1, 0.f);
        b0 = fmaxf(b0, 0.f);
        b1 = fmaxf(b1, 0.f);
    }
    Xb[(size_t)v0 * 64 + lane] = bf16pack(a0, a1);
    if (h1) Xb[(size_t)v1 * 64 + lane] = bf16pack(b0, b1);
}

// ---------------- edge scoring: 4 label edges per wave (bias pre-folded) ----
__global__ __launch_bounds__(256) void score_kernel(const int* __restrict__ ea,
                                                    const int* __restrict__ eb,
                                                    const unsigned int* __restrict__ Xb,
                                                    float* __restrict__ out) {
    int wbase = (blockIdx.x * 4 + (threadIdx.x >> 6)) * 4;
    int lane = threadIdx.x & 63;
    if (wbase >= N_LABEL) return;
    int ne = N_LABEL - wbase;
    if (ne > 4) ne = 4;

    unsigned int ua[4], ub[4];
#pragma unroll
    for (int e = 0; e < 4; ++e)
        if (e < ne) {
            int ia = ea[wbase + e], ib = eb[wbase + e];
            ua[e] = Xb[(size_t)ia * 64 + lane];
            ub[e] = Xb[(size_t)ib * 64 + lane];
        }
#pragma unroll
    for (int e = 0; e < 4; ++e)
        if (e < ne) {
            float p = bflo(ua[e]) * bflo(ub[e]) + bfhi(ua[e]) * bfhi(ub[e]);
#pragma unroll
            for (int off = 32; off > 0; off >>= 1) p += __shfl_down(p, off);
            if (lane == 0) out[wbase + e] = p;
        }
}

extern "C" void kernel_launch(void* const* d_in, const int* in_sizes, int n_in,
                              void* d_out, int out_size, void* d_ws, size_t ws_size,
                              hipStream_t stream) {
    const float* feat = (const float*)d_in[0];
    const int* ei = (const int*)d_in[1];
    const int* eli = (const int*)d_in[2];
    const float* W1 = (const float*)d_in[3];
    const float* b1 = (const float*)d_in[4];
    const float* W2 = (const float*)d_in[5];
    const float* b2 = (const float*)d_in[6];
    float* out = (float*)d_out;

    const int* src = ei;
    const int* dst = ei + N_EDGES;
    const int* la = eli;
    const int* lb = eli + N_LABEL;

    int* gcur = (int*)d_ws;                                   // NB (pad 1024)
    int* row_ptr = gcur + 1024;                               // N+4 ints
    float* dinv = (float*)(row_ptr + N_NODES + 4);            // N
    unsigned short* wt2 = (unsigned short*)(dinv + N_NODES);  // 16384 ushort
    int* packed = (int*)(wt2 + 16384);                        // E ints (4 MB)
    unsigned int* Hb = (unsigned int*)(packed + N_EDGES);     // N*64 uints
    unsigned int* Xb = Hb + (size_t)N_NODES * 64;             // N*64 uints
    unsigned int* temp = Xb;  // pass1/2 temp (6.4 MB) aliases Xb (dead til agg1)

    const int TB = 256;
    int gGemm = (N_NODES + BM - 1) / BM;  // 782
    int gAgg = (N_NODES + 7) / 8;         // 12500
    int gScore = (N_LABEL + 15) / 16;     // 12500

    hipMemsetAsync(gcur, 0, NB * sizeof(int), stream);

    // front: gemm1 || pass1 || wt2-conversion (all independent)
    fused_front<<<G_GEMM + P1_BLOCKS + G_W2BF, TB, 0, stream>>>(
        feat, W1, Hb, src, dst, gcur, temp, W2, wt2);

    // CSR fine sort (short, the only serial CSR stage left)
    pass2_sort<<<NB, TB, 0, stream>>>(gcur, temp, row_ptr, dinv, packed);

    // layer 1 aggregate
    aggregate<true><<<gAgg, TB, 0, stream>>>(Hb, packed, row_ptr, dinv, b1, Xb);

    // layer 2
    gemm128_mfma_bf16<<<gGemm, TB, 0, stream>>>(Xb, wt2, Hb, N_NODES);
    aggregate<false><<<gAgg, TB, 0, stream>>>(Hb, packed, row_ptr, dinv, b2, Xb);

    // scoring (b2 already folded into Xb)
    score_kernel<<<gScore, TB, 0, stream>>>(la, lb, Xb, out);
}

// Round 5
// 282.433 us; speedup vs baseline: 1.0727x; 1.0727x over previous
//
#include <hip/hip_runtime.h>
#include <hip/hip_bf16.h>

// GCN link-prediction: 2x GCNConv(128->128) + edge dot scoring.
// Round 17: REVERT R16's in-GEMM f32-W staging (column-strided 4B reads x782
// blocks violated R11 in staging form: +20us). Back to R15 structure
// (pre-converted wt1/wt2, coalesced 16B staging, {gemm1 || pass2} fused),
// keeping R16's aggregate ordering (issue gathers before dinv shuffle) and
// adding chunk-level p-prefetch so the packed-load wait never blocks gather
// issue (free for deg<=32 nodes: guard kills the load).
// LESSONS BANKED:
// - aggregate gather: pinned at ~3.65 TB/s random-64B fabric floor.
// - never fuse latency-bound gather with reg/LDS-heavy MFMA (R10).
// - never read MFMA B-frags strided from global - INCLUDING LDS staging
//   reads; pre-convert W coalesced (R11, R16: +20us).
// - random 8B scatter = 8x write amplification; atomics+scatter are
//   fabric-THROUGHPUT-bound, overlap doesn't help (R13).
// - CSR via 2-pass LDS counting sort >> 1M global atomics (R14: -57us).
// - dependent gather in meta path must not precede bulk-gather issue (R15).

#define N_NODES 100000
#define N_EDGES 1000000
#define N_LABEL 200000
#define D_FEAT 128
#define BM 128

#define NB 782        // coarse buckets: ceil(100000/128) nodes each
#define BCAP 2048     // temp capacity per bucket (mean 1279, +6sigma ~1500)
#define P1_EPT 16     // pass1 edges per thread
#define P1_BLOCKS 245 // ceil(1e6/4096)
#define G_GEMM 782    // ceil(100000/128)

typedef short bf16x8 __attribute__((ext_vector_type(8)));
typedef float f32x4 __attribute__((ext_vector_type(4)));

// ---- bf16 helpers (RNE) ----
__device__ inline unsigned int f2bf(float x) {
    unsigned int u = __float_as_uint(x);
    return (u + 0x7FFFu + ((u >> 16) & 1u)) >> 16;
}
__device__ inline unsigned int bf16pack(float a, float b) {
    return f2bf(a) | (f2bf(b) << 16);
}
__device__ inline float bflo(unsigned int u) { return __uint_as_float(u << 16); }
__device__ inline float bfhi(unsigned int u) { return __uint_as_float(u & 0xFFFF0000u); }

// ---------------- pass 1: coarse bucket by dst>>7 (+ W->bf16 merged) --------
__global__ __launch_bounds__(256) void pass1_bucket_w2bf(
    const int* __restrict__ src, const int* __restrict__ dst,
    int* __restrict__ gcur, unsigned int* __restrict__ temp,
    const float* __restrict__ W1, const float* __restrict__ W2,
    unsigned short* __restrict__ Wt1, unsigned short* __restrict__ Wt2) {
    int b = blockIdx.x, t = threadIdx.x;
    if (b >= P1_BLOCKS) {
        int i = (b - P1_BLOCKS) * 256 + t;  // 0..32767
        const float* W = (i < 16384) ? W1 : W2;
        unsigned short* Wt = (i < 16384) ? Wt1 : Wt2;
        int j = i & 16383;
        int n = j >> 7, k = j & 127;
        Wt[j] = (unsigned short)f2bf(W[(size_t)k * 128 + n]);
        return;
    }
    __shared__ int hist[NB], base[NB];
    for (int i = t; i < NB; i += 256) hist[i] = 0;
    __syncthreads();

    int se[P1_EPT], de[P1_EPT], rk[P1_EPT];
    int e0 = b * (P1_EPT * 256) + t;
#pragma unroll
    for (int j = 0; j < P1_EPT; ++j) {
        int e = e0 + j * 256;
        if (e < N_EDGES) {
            se[j] = src[e];
            de[j] = dst[e];
            rk[j] = atomicAdd(&hist[de[j] >> 7], 1);
        }
    }
    __syncthreads();
    for (int i = t; i < NB; i += 256) {
        int h = hist[i];
        base[i] = h ? atomicAdd(&gcur[i], h) : 0;
    }
    __syncthreads();
#pragma unroll
    for (int j = 0; j < P1_EPT; ++j) {
        int e = e0 + j * 256;
        if (e < N_EDGES) {
            int k = de[j] >> 7;
            int pos = base[k] + rk[j];
            if (pos < BCAP)
                temp[(size_t)k * BCAP + pos] =
                    (unsigned int)(((de[j] & 127) << 17) | se[j]);
        }
    }
}

// ---------------- MFMA GEMM body, LDS-staged bf16 W ----------------
template <bool BF16_IN>
__device__ __forceinline__ void gemm_body(const void* __restrict__ Xv,
                                          const unsigned short* __restrict__ Wt,
                                          unsigned int* __restrict__ Y,
                                          int nrows, int bid, short* Ws) {
    int t = threadIdx.x;
#pragma unroll
    for (int i = 0; i < 8; ++i) {
        int c = i * 256 + t;
        int n = c >> 4, q = c & 15;
        uint4 v = *(const uint4*)&Wt[(size_t)n * 128 + q * 8];
        *(uint4*)&Ws[n * 128 + ((q ^ (n & 15)) << 3)] = v;
    }
    __syncthreads();

    int wv = t >> 6;
    int lane = t & 63, l16 = lane & 15, quad = lane >> 4;
    int rbase = bid * BM + wv * 32;

    f32x4 acc[2][8];
#pragma unroll
    for (int rt = 0; rt < 2; ++rt)
#pragma unroll
        for (int nt = 0; nt < 8; ++nt) acc[rt][nt] = (f32x4){0.f, 0.f, 0.f, 0.f};

#pragma unroll
    for (int kb = 0; kb < 4; ++kb) {
        bf16x8 af[2];
#pragma unroll
        for (int rt = 0; rt < 2; ++rt) {
            int row = rbase + rt * 16 + l16;
            if (row > nrows - 1) row = nrows - 1;
            if constexpr (BF16_IN) {
                const unsigned int* Xb = (const unsigned int*)Xv;
                af[rt] = *(const bf16x8*)&Xb[(size_t)row * 64 + kb * 16 + quad * 4];
            } else {
                const float* X = (const float*)Xv;
                float4 fa = ((const float4*)X)[(size_t)row * 32 + kb * 8 + quad * 2];
                float4 fb = ((const float4*)X)[(size_t)row * 32 + kb * 8 + quad * 2 + 1];
                union { uint4 u; bf16x8 v; } cv;
                cv.u.x = bf16pack(fa.x, fa.y);
                cv.u.y = bf16pack(fa.z, fa.w);
                cv.u.z = bf16pack(fb.x, fb.y);
                cv.u.w = bf16pack(fb.z, fb.w);
                af[rt] = cv.v;
            }
        }
        bf16x8 bfr[8];
#pragma unroll
        for (int nt = 0; nt < 8; ++nt) {
            int n = nt * 16 + l16;
            bfr[nt] = *(const bf16x8*)&Ws[n * 128 + (((kb * 4 + quad) ^ l16) << 3)];
        }
#pragma unroll
        for (int rt = 0; rt < 2; ++rt)
#pragma unroll
            for (int nt = 0; nt < 8; ++nt)
                acc[rt][nt] = __builtin_amdgcn_mfma_f32_16x16x32_bf16(
                    af[rt], bfr[nt], acc[rt][nt], 0, 0, 0);
    }

    short* Ys = (short*)Y;
#pragma unroll
    for (int rt = 0; rt < 2; ++rt)
#pragma unroll
        for (int reg = 0; reg < 4; ++reg) {
            int row = rbase + rt * 16 + quad * 4 + reg;
            if (row < nrows) {
#pragma unroll
                for (int nt = 0; nt < 8; ++nt)
                    Ys[(size_t)row * 128 + nt * 16 + l16] = (short)f2bf(acc[rt][nt][reg]);
            }
        }
}

// standalone GEMM (layer 2, bf16 input)
__global__ __launch_bounds__(256) void gemm128_mfma_bf16(const unsigned int* __restrict__ Xb,
                                                         const unsigned short* __restrict__ Wt,
                                                         unsigned int* __restrict__ Y,
                                                         int nrows) {
    __shared__ __align__(16) short Ws[128 * 128];
    gemm_body<true>(Xb, Wt, Y, nrows, blockIdx.x, Ws);
}

// ---------------- fused: gemm1 (f32 input) || pass2 fine sort --------------
__global__ __launch_bounds__(256) void fused_gemm1_pass2(
    const float* __restrict__ feat, const unsigned short* __restrict__ wt1,
    unsigned int* __restrict__ Hb, const int* __restrict__ gcur,
    const unsigned int* __restrict__ temp, int* __restrict__ row_ptr,
    float* __restrict__ dinv, int* __restrict__ packed) {
    __shared__ __align__(16) short Ws[128 * 128];  // gemm tile / pass2 union
    int b = blockIdx.x, t = threadIdx.x;
    if (b < G_GEMM) {
        gemm_body<false>(feat, wt1, Hb, N_NODES, b, Ws);
        return;
    }
    int k = b - G_GEMM;
    unsigned int* ed = (unsigned int*)Ws;  // BCAP uints (8 KB)
    int* hist = (int*)(ed + BCAP);         // 128
    int* rp = hist + 128;                  // 128
    int* cur = rp + 128;                   // 128
    int* sc = cur + 128;                   // 128
    int* red = sc + 128;                   // 256

    // gbase = sum of gcur[j] for j<k (gcur tiny, L2-hot)
    int part = 0;
    for (int j = t; j < NB; j += 256)
        if (j < k) part += gcur[j];
    red[t] = part;
    __syncthreads();
    for (int off = 128; off > 0; off >>= 1) {
        if (t < off) red[t] += red[t + off];
        __syncthreads();
    }
    int gbase = red[0];
    int nk = gcur[k];
    if (nk > BCAP) nk = BCAP;

    if (t < 128) { hist[t] = 0; cur[t] = 0; }
    __syncthreads();
    for (int i = t; i < nk; i += 256) {
        unsigned int v = temp[(size_t)k * BCAP + i];
        ed[i] = v;
        atomicAdd(&hist[v >> 17], 1);
    }
    __syncthreads();

    // exclusive scan over 128 bins
    if (t < 128) sc[t] = hist[t];
    __syncthreads();
    for (int off = 1; off < 128; off <<= 1) {
        int a = (t < 128 && t >= off) ? sc[t - off] : 0;
        __syncthreads();
        if (t < 128) sc[t] += a;
        __syncthreads();
    }
    if (t < 128) {
        rp[t] = sc[t] - hist[t];
        int n = k * 128 + t;
        if (n < N_NODES) {
            row_ptr[n] = gbase + rp[t];
            dinv[n] = rsqrtf((float)(hist[t] + 1));  // +1 self-loop
        }
    }
    if (k == NB - 1 && t == 0) row_ptr[N_NODES] = N_EDGES;
    __syncthreads();

    for (int i = t; i < nk; i += 256) {
        unsigned int v = ed[i];
        int dl = v >> 17;
        int r = atomicAdd(&cur[dl], 1);
        packed[gbase + rp[dl] + r] = (int)(v & 0x1FFFF);
    }
}

// ---------------- gather-aggregate: 2 nodes/wave, 16 gathers in flight ----
// packed = src only (4B/edge). x[v] = dv*(dv*H[v] + sum_s dinv[s]*H[s]) + b.
// Per chunk: p preloaded (prologue / previous-iter prefetch) -> shuffle src
// -> ISSUE 16 row gathers -> prefetch next-chunk p -> shuffle dinv -> FMA.
// dinv[p] issues masked at chunk top; its latency hides under the gathers.
template <bool RELU>
__global__ __launch_bounds__(256) void aggregate(const unsigned int* __restrict__ Hb,
                                                 const int* __restrict__ packed,
                                                 const int* __restrict__ row_ptr,
                                                 const float* __restrict__ dinv,
                                                 const float* __restrict__ bias,
                                                 unsigned int* __restrict__ Xb) {
    int v0 = blockIdx.x * 8 + (threadIdx.x >> 6) * 2;
    int v1 = v0 + 1;
    int lane = threadIdx.x & 63;
    if (v0 >= N_NODES) return;
    bool h1 = (v1 < N_NODES);

    int st0 = row_ptr[v0], en0 = row_ptr[v0 + 1];
    int st1 = h1 ? row_ptr[v1] : 0, en1 = h1 ? row_ptr[v1 + 1] : 0;
    float dv0 = dinv[v0];
    float dv1 = h1 ? dinv[v1] : 0.f;

    unsigned int su0 = Hb[(size_t)v0 * 64 + lane];
    float a0 = dv0 * bflo(su0), a1 = dv0 * bfhi(su0);
    unsigned int su1 = h1 ? Hb[(size_t)v1 * 64 + lane] : 0u;
    float b0 = dv1 * bflo(su1), b1 = dv1 * bfhi(su1);

    // meta prefetch for first chunk
    int p = 0;
    if (lane < 32) {
        if (st0 + lane < en0) p = packed[st0 + lane];
    } else {
        if (st1 + lane - 32 < en1) p = packed[st1 + lane - 32];
    }

    for (int c0 = st0, c1 = st1; c0 < en0 || c1 < en1; c0 += 32, c1 += 32) {
        int n0 = en0 - c0; n0 = n0 < 0 ? 0 : (n0 > 32 ? 32 : n0);
        int n1 = en1 - c1; n1 = n1 < 0 ? 0 : (n1 > 32 ? 32 : n1);
        bool act = (lane < 32) ? (lane < n0) : (lane - 32 < n1);
        float dld = dinv[p];          // p=0 for inactive lanes: safe addr
        float d = act ? dld : 0.f;    // masked after load

        int nmax = n0 > n1 ? n0 : n1;
        int pn = 0;
        bool pref = false;
        for (int j = 0; j < nmax; j += 8) {
            int sA[8], sB[8];
#pragma unroll
            for (int q = 0; q < 8; ++q) {
                sA[q] = __shfl(p, j + q);
                sB[q] = __shfl(p, 32 + j + q);
            }
            unsigned int uA[8], uB[8];
#pragma unroll
            for (int q = 0; q < 8; ++q) {
                uA[q] = Hb[(size_t)sA[q] * 64 + lane];
                uB[q] = Hb[(size_t)sB[q] * 64 + lane];
            }
            if (!pref) {  // prefetch next-chunk meta under the first gathers
                pref = true;
                if (lane < 32) {
                    if (c0 + 32 + lane < en0) pn = packed[c0 + 32 + lane];
                } else {
                    if (c1 + lane < en1) pn = packed[c1 + lane];
                }
            }
            float dA[8], dB[8];
#pragma unroll
            for (int q = 0; q < 8; ++q) {
                dA[q] = __shfl(d, j + q);
                dB[q] = __shfl(d, 32 + j + q);
            }
#pragma unroll
            for (int q = 0; q < 8; ++q) {
                a0 = fmaf(dA[q], bflo(uA[q]), a0);
                a1 = fmaf(dA[q], bfhi(uA[q]), a1);
                b0 = fmaf(dB[q], bflo(uB[q]), b0);
                b1 = fmaf(dB[q], bfhi(uB[q]), b1);
            }
        }
        p = pn;
    }

    float2 bb = ((const float2*)bias)[lane];
    a0 = fmaf(a0, dv0, bb.x);
    a1 = fmaf(a1, dv0, bb.y);
    b0 = fmaf(b0, dv1, bb.x);
    b1 = fmaf(b1, dv1, bb.y);
    if (RELU) {
        a0 = fmaxf(a0, 0.f);
        a1 = fmaxf(a1, 0.f);
        b0 = fmaxf(b0, 0.f);
        b1 = fmaxf(b1, 0.f);
    }
    Xb[(size_t)v0 * 64 + lane] = bf16pack(a0, a1);
    if (h1) Xb[(size_t)v1 * 64 + lane] = bf16pack(b0, b1);
}

// ---------------- edge scoring: 4 label edges per wave (bias pre-folded) ----
__global__ __launch_bounds__(256) void score_kernel(const int* __restrict__ ea,
                                                    const int* __restrict__ eb,
                                                    const unsigned int* __restrict__ Xb,
                                                    float* __restrict__ out) {
    int wbase = (blockIdx.x * 4 + (threadIdx.x >> 6)) * 4;
    int lane = threadIdx.x & 63;
    if (wbase >= N_LABEL) return;
    int ne = N_LABEL - wbase;
    if (ne > 4) ne = 4;

    unsigned int ua[4], ub[4];
#pragma unroll
    for (int e = 0; e < 4; ++e)
        if (e < ne) {
            int ia = ea[wbase + e], ib = eb[wbase + e];
            ua[e] = Xb[(size_t)ia * 64 + lane];
            ub[e] = Xb[(size_t)ib * 64 + lane];
        }
#pragma unroll
    for (int e = 0; e < 4; ++e)
        if (e < ne) {
            float p = bflo(ua[e]) * bflo(ub[e]) + bfhi(ua[e]) * bfhi(ub[e]);
#pragma unroll
            for (int off = 32; off > 0; off >>= 1) p += __shfl_down(p, off);
            if (lane == 0) out[wbase + e] = p;
        }
}

extern "C" void kernel_launch(void* const* d_in, const int* in_sizes, int n_in,
                              void* d_out, int out_size, void* d_ws, size_t ws_size,
                              hipStream_t stream) {
    const float* feat = (const float*)d_in[0];
    const int* ei = (const int*)d_in[1];
    const int* eli = (const int*)d_in[2];
    const float* W1 = (const float*)d_in[3];
    const float* b1 = (const float*)d_in[4];
    const float* W2 = (const float*)d_in[5];
    const float* b2 = (const float*)d_in[6];
    float* out = (float*)d_out;

    const int* src = ei;
    const int* dst = ei + N_EDGES;
    const int* la = eli;
    const int* lb = eli + N_LABEL;

    int* gcur = (int*)d_ws;                                   // NB (pad 1024)
    int* row_ptr = gcur + 1024;                               // N+4 ints
    float* dinv = (float*)(row_ptr + N_NODES + 4);            // N
    unsigned short* wt1 = (unsigned short*)(dinv + N_NODES);  // 16384 ushort
    unsigned short* wt2 = wt1 + 16384;                        // 16384 ushort
    int* packed = (int*)(wt2 + 16384);                        // E ints (4 MB)
    unsigned int* Hb = (unsigned int*)(packed + N_EDGES);     // N*64 uints
    unsigned int* Xb = Hb + (size_t)N_NODES * 64;             // N*64 uints
    unsigned int* temp = Xb;  // pass1/2 temp (6.4 MB) aliases Xb (dead til agg1)

    const int TB = 256;
    int gGemm = (N_NODES + BM - 1) / BM;  // 782
    int gAgg = (N_NODES + 7) / 8;         // 12500
    int gScore = (N_LABEL + 15) / 16;     // 12500

    hipMemsetAsync(gcur, 0, NB * sizeof(int), stream);

    // CSR coarse bucket (+ W conversion folded in)
    pass1_bucket_w2bf<<<P1_BLOCKS + 128, TB, 0, stream>>>(src, dst, gcur, temp,
                                                          W1, W2, wt1, wt2);

    // gemm1 || pass2 fine sort (independent)
    fused_gemm1_pass2<<<G_GEMM + NB, TB, 0, stream>>>(feat, wt1, Hb, gcur, temp,
                                                      row_ptr, dinv, packed);

    // layer 1 aggregate
    aggregate<true><<<gAgg, TB, 0, stream>>>(Hb, packed, row_ptr, dinv, b1, Xb);

    // layer 2
    gemm128_mfma_bf16<<<gGemm, TB, 0, stream>>>(Xb, wt2, Hb, N_NODES);
    aggregate<false><<<gAgg, TB, 0, stream>>>(Hb, packed, row_ptr, dinv, b2, Xb);

    // scoring (b2 already folded into Xb)
    score_kernel<<<gScore, TB, 0, stream>>>(la, lb, Xb, out);
}

// Round 6
// 279.407 us; speedup vs baseline: 1.0844x; 1.0108x over previous
//
#include <hip/hip_runtime.h>
#include <hip/hip_bf16.h>

// GCN link-prediction: 2x GCNConv(128->128) + edge dot scoring.
// Round 18: overlap repair. pass1 (the longest un-overlapped front kernel)
// now runs INSIDE the gemm1 launch ({gemm1 || pass1}); W-conversion +
// gcur-zero move to a tiny launch0 (replaces hipMemset dispatch); pass2
// (~8us) runs standalone after. Front-end: 1+P+max(G1,8) -> 3+max(G1,P)+8.
// gemm_body/aggregate/score untouched (proven). LESSONS BANKED:
// - aggregate gather: pinned at ~3.65 TB/s random-64B fabric floor; FETCH
//   181MB invariant; issue-order micro-tuning is noise (R17).
// - never fuse latency-bound gather with reg/LDS-heavy MFMA (R10).
// - never read MFMA B-frags strided from global - INCLUDING LDS staging
//   reads; pre-convert W coalesced (R11, R16: +20us).
// - random 8B scatter = 8x write amplification; atomics+scatter are
//   fabric-THROUGHPUT-bound, overlap doesn't help (R13).
// - CSR via 2-pass LDS counting sort >> 1M global atomics (R14: -57us).

#define N_NODES 100000
#define N_EDGES 1000000
#define N_LABEL 200000
#define D_FEAT 128
#define BM 128

#define NB 782        // coarse buckets: ceil(100000/128) nodes each
#define BCAP 2048     // temp capacity per bucket (mean 1279, +6sigma ~1500)
#define P1_EPT 16     // pass1 edges per thread
#define P1_BLOCKS 245 // ceil(1e6/4096)
#define G_GEMM 782    // ceil(100000/128)
#define G_CONV 128    // W1+W2 conversion blocks (32768 elems / 256)

typedef short bf16x8 __attribute__((ext_vector_type(8)));
typedef float f32x4 __attribute__((ext_vector_type(4)));

// ---- bf16 helpers (RNE) ----
__device__ inline unsigned int f2bf(float x) {
    unsigned int u = __float_as_uint(x);
    return (u + 0x7FFFu + ((u >> 16) & 1u)) >> 16;
}
__device__ inline unsigned int bf16pack(float a, float b) {
    return f2bf(a) | (f2bf(b) << 16);
}
__device__ inline float bflo(unsigned int u) { return __uint_as_float(u << 16); }
__device__ inline float bfhi(unsigned int u) { return __uint_as_float(u & 0xFFFF0000u); }

// ---------------- launch0: W->bf16 transpose + gcur zero --------------------
__global__ __launch_bounds__(256) void w2bf_zero(
    const float* __restrict__ W1, const float* __restrict__ W2,
    unsigned short* __restrict__ Wt1, unsigned short* __restrict__ Wt2,
    int* __restrict__ gcur) {
    int b = blockIdx.x, t = threadIdx.x;
    if (b == G_CONV) {  // zero 1024 ints of gcur
        ((int4*)gcur)[t] = make_int4(0, 0, 0, 0);
        return;
    }
    int i = b * 256 + t;  // 0..32767
    const float* W = (i < 16384) ? W1 : W2;
    unsigned short* Wt = (i < 16384) ? Wt1 : Wt2;
    int j = i & 16383;
    int n = j >> 7, k = j & 127;
    Wt[j] = (unsigned short)f2bf(W[(size_t)k * 128 + n]);
}

// ---------------- MFMA GEMM body, LDS-staged bf16 W ----------------
template <bool BF16_IN>
__device__ __forceinline__ void gemm_body(const void* __restrict__ Xv,
                                          const unsigned short* __restrict__ Wt,
                                          unsigned int* __restrict__ Y,
                                          int nrows, int bid, short* Ws) {
    int t = threadIdx.x;
#pragma unroll
    for (int i = 0; i < 8; ++i) {
        int c = i * 256 + t;
        int n = c >> 4, q = c & 15;
        uint4 v = *(const uint4*)&Wt[(size_t)n * 128 + q * 8];
        *(uint4*)&Ws[n * 128 + ((q ^ (n & 15)) << 3)] = v;
    }
    __syncthreads();

    int wv = t >> 6;
    int lane = t & 63, l16 = lane & 15, quad = lane >> 4;
    int rbase = bid * BM + wv * 32;

    f32x4 acc[2][8];
#pragma unroll
    for (int rt = 0; rt < 2; ++rt)
#pragma unroll
        for (int nt = 0; nt < 8; ++nt) acc[rt][nt] = (f32x4){0.f, 0.f, 0.f, 0.f};

#pragma unroll
    for (int kb = 0; kb < 4; ++kb) {
        bf16x8 af[2];
#pragma unroll
        for (int rt = 0; rt < 2; ++rt) {
            int row = rbase + rt * 16 + l16;
            if (row > nrows - 1) row = nrows - 1;
            if constexpr (BF16_IN) {
                const unsigned int* Xb = (const unsigned int*)Xv;
                af[rt] = *(const bf16x8*)&Xb[(size_t)row * 64 + kb * 16 + quad * 4];
            } else {
                const float* X = (const float*)Xv;
                float4 fa = ((const float4*)X)[(size_t)row * 32 + kb * 8 + quad * 2];
                float4 fb = ((const float4*)X)[(size_t)row * 32 + kb * 8 + quad * 2 + 1];
                union { uint4 u; bf16x8 v; } cv;
                cv.u.x = bf16pack(fa.x, fa.y);
                cv.u.y = bf16pack(fa.z, fa.w);
                cv.u.z = bf16pack(fb.x, fb.y);
                cv.u.w = bf16pack(fb.z, fb.w);
                af[rt] = cv.v;
            }
        }
        bf16x8 bfr[8];
#pragma unroll
        for (int nt = 0; nt < 8; ++nt) {
            int n = nt * 16 + l16;
            bfr[nt] = *(const bf16x8*)&Ws[n * 128 + (((kb * 4 + quad) ^ l16) << 3)];
        }
#pragma unroll
        for (int rt = 0; rt < 2; ++rt)
#pragma unroll
            for (int nt = 0; nt < 8; ++nt)
                acc[rt][nt] = __builtin_amdgcn_mfma_f32_16x16x32_bf16(
                    af[rt], bfr[nt], acc[rt][nt], 0, 0, 0);
    }

    short* Ys = (short*)Y;
#pragma unroll
    for (int rt = 0; rt < 2; ++rt)
#pragma unroll
        for (int reg = 0; reg < 4; ++reg) {
            int row = rbase + rt * 16 + quad * 4 + reg;
            if (row < nrows) {
#pragma unroll
                for (int nt = 0; nt < 8; ++nt)
                    Ys[(size_t)row * 128 + nt * 16 + l16] = (short)f2bf(acc[rt][nt][reg]);
            }
        }
}

// standalone GEMM (layer 2, bf16 input)
__global__ __launch_bounds__(256) void gemm128_mfma_bf16(const unsigned int* __restrict__ Xb,
                                                         const unsigned short* __restrict__ Wt,
                                                         unsigned int* __restrict__ Y,
                                                         int nrows) {
    __shared__ __align__(16) short Ws[128 * 128];
    gemm_body<true>(Xb, Wt, Y, nrows, blockIdx.x, Ws);
}

// ---------------- fused: gemm1 (f32 input) || pass1 coarse bucket ----------
// pass1: LDS hist over 782 buckets -> per-edge rank; 1 global atomic per
// (block,bucket); scatter packed 24-bit ((dst&127)<<17|src) in ~5-edge runs.
// pass1's 6.3 KB LDS unions inside gemm's 32 KB Ws.
__global__ __launch_bounds__(256) void fused_gemm1_pass1(
    const float* __restrict__ feat, const unsigned short* __restrict__ wt1,
    unsigned int* __restrict__ Hb,
    const int* __restrict__ src, const int* __restrict__ dst,
    int* __restrict__ gcur, unsigned int* __restrict__ temp) {
    __shared__ __align__(16) short Ws[128 * 128];  // gemm tile / pass1 union
    int b = blockIdx.x, t = threadIdx.x;
    if (b < G_GEMM) {
        gemm_body<false>(feat, wt1, Hb, N_NODES, b, Ws);
        return;
    }
    b -= G_GEMM;
    int* hist = (int*)Ws;   // NB ints
    int* base = hist + NB;  // NB ints
    for (int i = t; i < NB; i += 256) hist[i] = 0;
    __syncthreads();

    int se[P1_EPT], de[P1_EPT], rk[P1_EPT];
    int e0 = b * (P1_EPT * 256) + t;
#pragma unroll
    for (int j = 0; j < P1_EPT; ++j) {
        int e = e0 + j * 256;
        if (e < N_EDGES) {
            se[j] = src[e];
            de[j] = dst[e];
            rk[j] = atomicAdd(&hist[de[j] >> 7], 1);
        }
    }
    __syncthreads();
    for (int i = t; i < NB; i += 256) {
        int h = hist[i];
        base[i] = h ? atomicAdd(&gcur[i], h) : 0;
    }
    __syncthreads();
#pragma unroll
    for (int j = 0; j < P1_EPT; ++j) {
        int e = e0 + j * 256;
        if (e < N_EDGES) {
            int k = de[j] >> 7;
            int pos = base[k] + rk[j];
            if (pos < BCAP)
                temp[(size_t)k * BCAP + pos] =
                    (unsigned int)(((de[j] & 127) << 17) | se[j]);
        }
    }
}

// ---------------- pass 2: per-bucket LDS fine counting sort -----------------
__global__ __launch_bounds__(256) void pass2_sort(
    const int* __restrict__ gcur, const unsigned int* __restrict__ temp,
    int* __restrict__ row_ptr, float* __restrict__ dinv,
    int* __restrict__ packed) {
    int k = blockIdx.x, t = threadIdx.x;
    __shared__ unsigned int ed[BCAP];
    __shared__ int hist[128], rp[128], cur[128], sc[128];
    __shared__ int red[256];

    // gbase = sum of gcur[j] for j<k (gcur tiny, L2-hot)
    int part = 0;
    for (int j = t; j < NB; j += 256)
        if (j < k) part += gcur[j];
    red[t] = part;
    __syncthreads();
    for (int off = 128; off > 0; off >>= 1) {
        if (t < off) red[t] += red[t + off];
        __syncthreads();
    }
    int gbase = red[0];
    int nk = gcur[k];
    if (nk > BCAP) nk = BCAP;

    if (t < 128) { hist[t] = 0; cur[t] = 0; }
    __syncthreads();
    for (int i = t; i < nk; i += 256) {
        unsigned int v = temp[(size_t)k * BCAP + i];
        ed[i] = v;
        atomicAdd(&hist[v >> 17], 1);
    }
    __syncthreads();

    // exclusive scan over 128 bins
    if (t < 128) sc[t] = hist[t];
    __syncthreads();
    for (int off = 1; off < 128; off <<= 1) {
        int a = (t < 128 && t >= off) ? sc[t - off] : 0;
        __syncthreads();
        if (t < 128) sc[t] += a;
        __syncthreads();
    }
    if (t < 128) {
        rp[t] = sc[t] - hist[t];
        int n = k * 128 + t;
        if (n < N_NODES) {
            row_ptr[n] = gbase + rp[t];
            dinv[n] = rsqrtf((float)(hist[t] + 1));  // +1 self-loop
        }
    }
    if (k == NB - 1 && t == 0) row_ptr[N_NODES] = N_EDGES;
    __syncthreads();

    for (int i = t; i < nk; i += 256) {
        unsigned int v = ed[i];
        int dl = v >> 17;
        int r = atomicAdd(&cur[dl], 1);
        packed[gbase + rp[dl] + r] = (int)(v & 0x1FFFF);
    }
}

// ---------------- gather-aggregate: 2 nodes/wave, 16 gathers in flight ----
// packed = src only (4B/edge). x[v] = dv*(dv*H[v] + sum_s dinv[s]*H[s]) + b.
template <bool RELU>
__global__ __launch_bounds__(256) void aggregate(const unsigned int* __restrict__ Hb,
                                                 const int* __restrict__ packed,
                                                 const int* __restrict__ row_ptr,
                                                 const float* __restrict__ dinv,
                                                 const float* __restrict__ bias,
                                                 unsigned int* __restrict__ Xb) {
    int v0 = blockIdx.x * 8 + (threadIdx.x >> 6) * 2;
    int v1 = v0 + 1;
    int lane = threadIdx.x & 63;
    if (v0 >= N_NODES) return;
    bool h1 = (v1 < N_NODES);

    int st0 = row_ptr[v0], en0 = row_ptr[v0 + 1];
    int st1 = h1 ? row_ptr[v1] : 0, en1 = h1 ? row_ptr[v1 + 1] : 0;
    float dv0 = dinv[v0];
    float dv1 = h1 ? dinv[v1] : 0.f;

    unsigned int su0 = Hb[(size_t)v0 * 64 + lane];
    float a0 = dv0 * bflo(su0), a1 = dv0 * bfhi(su0);
    unsigned int su1 = h1 ? Hb[(size_t)v1 * 64 + lane] : 0u;
    float b0 = dv1 * bflo(su1), b1 = dv1 * bfhi(su1);

    // meta prefetch for first chunk
    int p = 0;
    if (lane < 32) {
        if (st0 + lane < en0) p = packed[st0 + lane];
    } else {
        if (st1 + lane - 32 < en1) p = packed[st1 + lane - 32];
    }

    for (int c0 = st0, c1 = st1; c0 < en0 || c1 < en1; c0 += 32, c1 += 32) {
        int n0 = en0 - c0; n0 = n0 < 0 ? 0 : (n0 > 32 ? 32 : n0);
        int n1 = en1 - c1; n1 = n1 < 0 ? 0 : (n1 > 32 ? 32 : n1);
        bool act = (lane < 32) ? (lane < n0) : (lane - 32 < n1);
        float dld = dinv[p];          // p=0 for inactive lanes: safe addr
        float d = act ? dld : 0.f;    // masked after load

        int nmax = n0 > n1 ? n0 : n1;
        int pn = 0;
        bool pref = false;
        for (int j = 0; j < nmax; j += 8) {
            int sA[8], sB[8];
#pragma unroll
            for (int q = 0; q < 8; ++q) {
                sA[q] = __shfl(p, j + q);
                sB[q] = __shfl(p, 32 + j + q);
            }
            unsigned int uA[8], uB[8];
#pragma unroll
            for (int q = 0; q < 8; ++q) {
                uA[q] = Hb[(size_t)sA[q] * 64 + lane];
                uB[q] = Hb[(size_t)sB[q] * 64 + lane];
            }
            if (!pref) {  // prefetch next-chunk meta under the first gathers
                pref = true;
                if (lane < 32) {
                    if (c0 + 32 + lane < en0) pn = packed[c0 + 32 + lane];
                } else {
                    if (c1 + lane < en1) pn = packed[c1 + lane];
                }
            }
            float dA[8], dB[8];
#pragma unroll
            for (int q = 0; q < 8; ++q) {
                dA[q] = __shfl(d, j + q);
                dB[q] = __shfl(d, 32 + j + q);
            }
#pragma unroll
            for (int q = 0; q < 8; ++q) {
                a0 = fmaf(dA[q], bflo(uA[q]), a0);
                a1 = fmaf(dA[q], bfhi(uA[q]), a1);
                b0 = fmaf(dB[q], bflo(uB[q]), b0);
                b1 = fmaf(dB[q], bfhi(uB[q]), b1);
            }
        }
        p = pn;
    }

    float2 bb = ((const float2*)bias)[lane];
    a0 = fmaf(a0, dv0, bb.x);
    a1 = fmaf(a1, dv0, bb.y);
    b0 = fmaf(b0, dv1, bb.x);
    b1 = fmaf(b1, dv1, bb.y);
    if (RELU) {
        a0 = fmaxf(a0, 0.f);
        a1 = fmaxf(a1, 0.f);
        b0 = fmaxf(b0, 0.f);
        b1 = fmaxf(b1, 0.f);
    }
    Xb[(size_t)v0 * 64 + lane] = bf16pack(a0, a1);
    if (h1) Xb[(size_t)v1 * 64 + lane] = bf16pack(b0, b1);
}

// ---------------- edge scoring: 4 label edges per wave (bias pre-folded) ----
__global__ __launch_bounds__(256) void score_kernel(const int* __restrict__ ea,
                                                    const int* __restrict__ eb,
                                                    const unsigned int* __restrict__ Xb,
                                                    float* __restrict__ out) {
    int wbase = (blockIdx.x * 4 + (threadIdx.x >> 6)) * 4;
    int lane = threadIdx.x & 63;
    if (wbase >= N_LABEL) return;
    int ne = N_LABEL - wbase;
    if (ne > 4) ne = 4;

    unsigned int ua[4], ub[4];
#pragma unroll
    for (int e = 0; e < 4; ++e)
        if (e < ne) {
            int ia = ea[wbase + e], ib = eb[wbase + e];
            ua[e] = Xb[(size_t)ia * 64 + lane];
            ub[e] = Xb[(size_t)ib * 64 + lane];
        }
#pragma unroll
    for (int e = 0; e < 4; ++e)
        if (e < ne) {
            float p = bflo(ua[e]) * bflo(ub[e]) + bfhi(ua[e]) * bfhi(ub[e]);
#pragma unroll
            for (int off = 32; off > 0; off >>= 1) p += __shfl_down(p, off);
            if (lane == 0) out[wbase + e] = p;
        }
}

extern "C" void kernel_launch(void* const* d_in, const int* in_sizes, int n_in,
                              void* d_out, int out_size, void* d_ws, size_t ws_size,
                              hipStream_t stream) {
    const float* feat = (const float*)d_in[0];
    const int* ei = (const int*)d_in[1];
    const int* eli = (const int*)d_in[2];
    const float* W1 = (const float*)d_in[3];
    const float* b1 = (const float*)d_in[4];
    const float* W2 = (const float*)d_in[5];
    const float* b2 = (const float*)d_in[6];
    float* out = (float*)d_out;

    const int* src = ei;
    const int* dst = ei + N_EDGES;
    const int* la = eli;
    const int* lb = eli + N_LABEL;

    int* gcur = (int*)d_ws;                                   // 1024 ints
    int* row_ptr = gcur + 1024;                               // N+4 ints
    float* dinv = (float*)(row_ptr + N_NODES + 4);            // N
    unsigned short* wt1 = (unsigned short*)(dinv + N_NODES);  // 16384 ushort
    unsigned short* wt2 = wt1 + 16384;                        // 16384 ushort
    int* packed = (int*)(wt2 + 16384);                        // E ints (4 MB)
    unsigned int* Hb = (unsigned int*)(packed + N_EDGES);     // N*64 uints
    unsigned int* Xb = Hb + (size_t)N_NODES * 64;             // N*64 uints
    unsigned int* temp = Xb;  // pass1/2 temp (6.4 MB) aliases Xb (dead til agg1)

    const int TB = 256;
    int gGemm = (N_NODES + BM - 1) / BM;  // 782
    int gAgg = (N_NODES + 7) / 8;         // 12500
    int gScore = (N_LABEL + 15) / 16;     // 12500

    // launch0: W conversion + gcur zero (replaces memset dispatch)
    w2bf_zero<<<G_CONV + 1, TB, 0, stream>>>(W1, W2, wt1, wt2, gcur);

    // gemm1 || pass1 (independent; pass1 was the longest un-overlapped stage)
    fused_gemm1_pass1<<<G_GEMM + P1_BLOCKS, TB, 0, stream>>>(
        feat, wt1, Hb, src, dst, gcur, temp);

    // CSR fine sort (short, serial)
    pass2_sort<<<NB, TB, 0, stream>>>(gcur, temp, row_ptr, dinv, packed);

    // layer 1 aggregate
    aggregate<true><<<gAgg, TB, 0, stream>>>(Hb, packed, row_ptr, dinv, b1, Xb);

    // layer 2
    gemm128_mfma_bf16<<<gGemm, TB, 0, stream>>>(Xb, wt2, Hb, N_NODES);
    aggregate<false><<<gAgg, TB, 0, stream>>>(Hb, packed, row_ptr, dinv, b2, Xb);

    // scoring (b2 already folded into Xb)
    score_kernel<<<gScore, TB, 0, stream>>>(la, lb, Xb, out);
}

// Round 7
// 278.445 us; speedup vs baseline: 1.0881x; 1.0035x over previous
//
#include <hip/hip_runtime.h>
#include <hip/hip_bf16.h>

// GCN link-prediction: 2x GCNConv(128->128) + edge dot scoring.
// Round 19: scatter-free CSR build. pass1 temp goes block-major: each block
// sorts its 4096 edges by bucket IN LDS (16KB + LDS scan), dumps its region
// with coalesced uint4 stores + writes per-block bucket offsets bofs[b][783].
// No global atomics (gcur/memset deleted), no partial-line scatter (R13/R18
// amplification gone) -> pass1 is pure stream and hides under gemm1.
// pass2 gathers bucket k's 245 short segments from L3-hot temp;
// gbase = sum_b bofs[b][k]. Aggregate/gemm/score untouched.
// LESSONS BANKED:
// - aggregate gather: pinned at ~3.65 TB/s random-64B fabric floor; FETCH
//   181MB invariant; issue-order micro-tuning is noise (R17).
// - never fuse latency-bound gather with reg/LDS-heavy MFMA (R10).
// - never read MFMA B-frags strided from global - INCLUDING LDS staging
//   reads; pre-convert W coalesced (R11, R16: +20us).
// - partial-line scatter = write-allocate amplification; atomics+scatter
//   are fabric-THROUGHPUT-bound, don't overlap with streaming (R13, R18).
// - CSR via LDS counting sort >> 1M global atomics (R14: -57us).

#define N_NODES 100000
#define N_EDGES 1000000
#define N_LABEL 200000
#define D_FEAT 128
#define BM 128

#define NB 782        // coarse buckets: ceil(100000/128) nodes each
#define BCAP 2048     // pass2 LDS capacity per bucket (mean 1279, +6sig ~1500)
#define P1_EPT 16     // pass1 edges per thread
#define P1_BLOCKS 245 // ceil(1e6/4096)
#define G_GEMM 782    // ceil(100000/128)
#define G_CONV 128    // W1+W2 conversion blocks (32768 elems / 256)

typedef short bf16x8 __attribute__((ext_vector_type(8)));
typedef float f32x4 __attribute__((ext_vector_type(4)));

// ---- bf16 helpers (RNE) ----
__device__ inline unsigned int f2bf(float x) {
    unsigned int u = __float_as_uint(x);
    return (u + 0x7FFFu + ((u >> 16) & 1u)) >> 16;
}
__device__ inline unsigned int bf16pack(float a, float b) {
    return f2bf(a) | (f2bf(b) << 16);
}
__device__ inline float bflo(unsigned int u) { return __uint_as_float(u << 16); }
__device__ inline float bfhi(unsigned int u) { return __uint_as_float(u & 0xFFFF0000u); }

// ---------------- launch0: W->bf16 transpose (weights only) -----------------
__global__ __launch_bounds__(256) void w2bf(
    const float* __restrict__ W1, const float* __restrict__ W2,
    unsigned short* __restrict__ Wt1, unsigned short* __restrict__ Wt2) {
    int i = blockIdx.x * 256 + threadIdx.x;  // 0..32767
    const float* W = (i < 16384) ? W1 : W2;
    unsigned short* Wt = (i < 16384) ? Wt1 : Wt2;
    int j = i & 16383;
    int n = j >> 7, k = j & 127;
    Wt[j] = (unsigned short)f2bf(W[(size_t)k * 128 + n]);
}

// ---------------- MFMA GEMM body, LDS-staged bf16 W ----------------
template <bool BF16_IN>
__device__ __forceinline__ void gemm_body(const void* __restrict__ Xv,
                                          const unsigned short* __restrict__ Wt,
                                          unsigned int* __restrict__ Y,
                                          int nrows, int bid, short* Ws) {
    int t = threadIdx.x;
#pragma unroll
    for (int i = 0; i < 8; ++i) {
        int c = i * 256 + t;
        int n = c >> 4, q = c & 15;
        uint4 v = *(const uint4*)&Wt[(size_t)n * 128 + q * 8];
        *(uint4*)&Ws[n * 128 + ((q ^ (n & 15)) << 3)] = v;
    }
    __syncthreads();

    int wv = t >> 6;
    int lane = t & 63, l16 = lane & 15, quad = lane >> 4;
    int rbase = bid * BM + wv * 32;

    f32x4 acc[2][8];
#pragma unroll
    for (int rt = 0; rt < 2; ++rt)
#pragma unroll
        for (int nt = 0; nt < 8; ++nt) acc[rt][nt] = (f32x4){0.f, 0.f, 0.f, 0.f};

#pragma unroll
    for (int kb = 0; kb < 4; ++kb) {
        bf16x8 af[2];
#pragma unroll
        for (int rt = 0; rt < 2; ++rt) {
            int row = rbase + rt * 16 + l16;
            if (row > nrows - 1) row = nrows - 1;
            if constexpr (BF16_IN) {
                const unsigned int* Xb = (const unsigned int*)Xv;
                af[rt] = *(const bf16x8*)&Xb[(size_t)row * 64 + kb * 16 + quad * 4];
            } else {
                const float* X = (const float*)Xv;
                float4 fa = ((const float4*)X)[(size_t)row * 32 + kb * 8 + quad * 2];
                float4 fb = ((const float4*)X)[(size_t)row * 32 + kb * 8 + quad * 2 + 1];
                union { uint4 u; bf16x8 v; } cv;
                cv.u.x = bf16pack(fa.x, fa.y);
                cv.u.y = bf16pack(fa.z, fa.w);
                cv.u.z = bf16pack(fb.x, fb.y);
                cv.u.w = bf16pack(fb.z, fb.w);
                af[rt] = cv.v;
            }
        }
        bf16x8 bfr[8];
#pragma unroll
        for (int nt = 0; nt < 8; ++nt) {
            int n = nt * 16 + l16;
            bfr[nt] = *(const bf16x8*)&Ws[n * 128 + (((kb * 4 + quad) ^ l16) << 3)];
        }
#pragma unroll
        for (int rt = 0; rt < 2; ++rt)
#pragma unroll
            for (int nt = 0; nt < 8; ++nt)
                acc[rt][nt] = __builtin_amdgcn_mfma_f32_16x16x32_bf16(
                    af[rt], bfr[nt], acc[rt][nt], 0, 0, 0);
    }

    short* Ys = (short*)Y;
#pragma unroll
    for (int rt = 0; rt < 2; ++rt)
#pragma unroll
        for (int reg = 0; reg < 4; ++reg) {
            int row = rbase + rt * 16 + quad * 4 + reg;
            if (row < nrows) {
#pragma unroll
                for (int nt = 0; nt < 8; ++nt)
                    Ys[(size_t)row * 128 + nt * 16 + l16] = (short)f2bf(acc[rt][nt][reg]);
            }
        }
}

// standalone GEMM (layer 2, bf16 input)
__global__ __launch_bounds__(256) void gemm128_mfma_bf16(const unsigned int* __restrict__ Xb,
                                                         const unsigned short* __restrict__ Wt,
                                                         unsigned int* __restrict__ Y,
                                                         int nrows) {
    __shared__ __align__(16) short Ws[128 * 128];
    gemm_body<true>(Xb, Wt, Y, nrows, blockIdx.x, Ws);
}

// ---------------- fused: gemm1 (f32 input) || pass1 (scatter-free) ---------
// pass1 block b: LDS hist over 1024 padded bins -> LDS scan -> records
// sorted into 16KB LDS buffer -> coalesced uint4 dump to temp[b*4096] +
// bofs[b][0..782] (exclusive offsets; [782]=block count). No global atomics.
__global__ __launch_bounds__(256) void fused_gemm1_pass1(
    const float* __restrict__ feat, const unsigned short* __restrict__ wt1,
    unsigned int* __restrict__ Hb,
    const int* __restrict__ src, const int* __restrict__ dst,
    unsigned int* __restrict__ temp, int* __restrict__ bofs) {
    __shared__ __align__(16) short Ws[128 * 128];  // gemm tile / pass1 union
    int b = blockIdx.x, t = threadIdx.x;
    if (b < G_GEMM) {
        gemm_body<false>(feat, wt1, Hb, N_NODES, b, Ws);
        return;
    }
    b -= G_GEMM;
    unsigned int* ed16 = (unsigned int*)Ws;  // 4096 u32 (16 KB)
    int* hist = (int*)(ed16 + 4096);         // 1024 ints (bins padded)
    int* red = hist + 1024;                  // 256

    for (int i = t; i < 1024; i += 256) hist[i] = 0;
    __syncthreads();

    int se[P1_EPT], de[P1_EPT], rk[P1_EPT];
    int e0 = b * 4096 + t;
#pragma unroll
    for (int j = 0; j < P1_EPT; ++j) {
        int e = e0 + j * 256;
        if (e < N_EDGES) {
            se[j] = src[e];
            de[j] = dst[e];
            rk[j] = atomicAdd(&hist[de[j] >> 7], 1);
        }
    }
    __syncthreads();

    // exclusive scan over 1024 bins: thread t owns bins 4t..4t+3
    int c0 = hist[4 * t], c1 = hist[4 * t + 1], c2 = hist[4 * t + 2], c3 = hist[4 * t + 3];
    int s = c0 + c1 + c2 + c3;
    red[t] = s;
    __syncthreads();
    for (int off = 1; off < 256; off <<= 1) {
        int a = (t >= off) ? red[t - off] : 0;
        __syncthreads();
        red[t] += a;
        __syncthreads();
    }
    int excl = red[t] - s;
    hist[4 * t] = excl;
    hist[4 * t + 1] = excl + c0;
    hist[4 * t + 2] = excl + c0 + c1;
    hist[4 * t + 3] = excl + c0 + c1 + c2;
    __syncthreads();

    // scatter records into LDS (bucket-sorted within block)
#pragma unroll
    for (int j = 0; j < P1_EPT; ++j) {
        int e = e0 + j * 256;
        if (e < N_EDGES) {
            int pos = hist[de[j] >> 7] + rk[j];
            ed16[pos] = (unsigned int)(((de[j] & 127) << 17) | se[j]);
        }
    }
    __syncthreads();

    // coalesced dump + bofs
#pragma unroll
    for (int i = 0; i < 4; ++i)
        ((uint4*)temp)[(size_t)b * 1024 + i * 256 + t] = ((uint4*)ed16)[i * 256 + t];
    for (int j = t; j < NB; j += 256) bofs[b * (NB + 1) + j] = hist[j];
    if (t == 0) {
        int cnt = N_EDGES - b * 4096;
        if (cnt > 4096) cnt = 4096;
        bofs[b * (NB + 1) + NB] = cnt;
    }
}

// ---------------- pass 2: per-bucket fine sort (segment gather) -------------
// Block k: gather its 245 segments from block-major temp (L3-hot),
// gbase = sum_b bofs[b][k], then LDS fine counting sort as before.
__global__ __launch_bounds__(256) void pass2_sort(
    const unsigned int* __restrict__ temp, const int* __restrict__ bofs,
    int* __restrict__ row_ptr, float* __restrict__ dinv,
    int* __restrict__ packed) {
    int k = blockIdx.x, t = threadIdx.x;
    __shared__ unsigned int ed[BCAP];
    __shared__ int hist[128], rp[128], cur[128], sc2[128];
    __shared__ int red[256], sc[256];

    int s_t = 0, len = 0;
    if (t < P1_BLOCKS) {
        s_t = bofs[t * (NB + 1) + k];
        len = bofs[t * (NB + 1) + k + 1] - s_t;
    }
    // gbase = sum_b s_b
    red[t] = s_t;
    __syncthreads();
    for (int off = 128; off > 0; off >>= 1) {
        if (t < off) red[t] += red[t + off];
        __syncthreads();
    }
    int gbase = red[0];
    __syncthreads();
    // dloc: exclusive scan of segment lengths
    sc[t] = len;
    __syncthreads();
    for (int off = 1; off < 256; off <<= 1) {
        int a = (t >= off) ? sc[t - off] : 0;
        __syncthreads();
        sc[t] += a;
        __syncthreads();
    }
    int dloc = sc[t] - len;
    int nk = sc[255];
    if (nk > BCAP) nk = BCAP;

    if (t < 128) { hist[t] = 0; cur[t] = 0; }
    __syncthreads();
    // gather segments into LDS
    for (int i = 0; i < len; ++i) {
        int d = dloc + i;
        if (d < BCAP) ed[d] = temp[(size_t)t * 4096 + s_t + i];
    }
    __syncthreads();
    for (int i = t; i < nk; i += 256) atomicAdd(&hist[ed[i] >> 17], 1);
    __syncthreads();

    // exclusive scan over 128 bins
    if (t < 128) sc2[t] = hist[t];
    __syncthreads();
    for (int off = 1; off < 128; off <<= 1) {
        int a = (t < 128 && t >= off) ? sc2[t - off] : 0;
        __syncthreads();
        if (t < 128) sc2[t] += a;
        __syncthreads();
    }
    if (t < 128) {
        rp[t] = sc2[t] - hist[t];
        int n = k * 128 + t;
        if (n < N_NODES) {
            row_ptr[n] = gbase + rp[t];
            dinv[n] = rsqrtf((float)(hist[t] + 1));  // +1 self-loop
        }
    }
    if (k == NB - 1 && t == 0) row_ptr[N_NODES] = N_EDGES;
    __syncthreads();

    for (int i = t; i < nk; i += 256) {
        unsigned int v = ed[i];
        int dl = v >> 17;
        int r = atomicAdd(&cur[dl], 1);
        packed[gbase + rp[dl] + r] = (int)(v & 0x1FFFF);
    }
}

// ---------------- gather-aggregate: 2 nodes/wave, 16 gathers in flight ----
// packed = src only (4B/edge). x[v] = dv*(dv*H[v] + sum_s dinv[s]*H[s]) + b.
template <bool RELU>
__global__ __launch_bounds__(256) void aggregate(const unsigned int* __restrict__ Hb,
                                                 const int* __restrict__ packed,
                                                 const int* __restrict__ row_ptr,
                                                 const float* __restrict__ dinv,
                                                 const float* __restrict__ bias,
                                                 unsigned int* __restrict__ Xb) {
    int v0 = blockIdx.x * 8 + (threadIdx.x >> 6) * 2;
    int v1 = v0 + 1;
    int lane = threadIdx.x & 63;
    if (v0 >= N_NODES) return;
    bool h1 = (v1 < N_NODES);

    int st0 = row_ptr[v0], en0 = row_ptr[v0 + 1];
    int st1 = h1 ? row_ptr[v1] : 0, en1 = h1 ? row_ptr[v1 + 1] : 0;
    float dv0 = dinv[v0];
    float dv1 = h1 ? dinv[v1] : 0.f;

    unsigned int su0 = Hb[(size_t)v0 * 64 + lane];
    float a0 = dv0 * bflo(su0), a1 = dv0 * bfhi(su0);
    unsigned int su1 = h1 ? Hb[(size_t)v1 * 64 + lane] : 0u;
    float b0 = dv1 * bflo(su1), b1 = dv1 * bfhi(su1);

    // meta prefetch for first chunk
    int p = 0;
    if (lane < 32) {
        if (st0 + lane < en0) p = packed[st0 + lane];
    } else {
        if (st1 + lane - 32 < en1) p = packed[st1 + lane - 32];
    }

    for (int c0 = st0, c1 = st1; c0 < en0 || c1 < en1; c0 += 32, c1 += 32) {
        int n0 = en0 - c0; n0 = n0 < 0 ? 0 : (n0 > 32 ? 32 : n0);
        int n1 = en1 - c1; n1 = n1 < 0 ? 0 : (n1 > 32 ? 32 : n1);
        bool act = (lane < 32) ? (lane < n0) : (lane - 32 < n1);
        float dld = dinv[p];          // p=0 for inactive lanes: safe addr
        float d = act ? dld : 0.f;    // masked after load

        int nmax = n0 > n1 ? n0 : n1;
        int pn = 0;
        bool pref = false;
        for (int j = 0; j < nmax; j += 8) {
            int sA[8], sB[8];
#pragma unroll
            for (int q = 0; q < 8; ++q) {
                sA[q] = __shfl(p, j + q);
                sB[q] = __shfl(p, 32 + j + q);
            }
            unsigned int uA[8], uB[8];
#pragma unroll
            for (int q = 0; q < 8; ++q) {
                uA[q] = Hb[(size_t)sA[q] * 64 + lane];
                uB[q] = Hb[(size_t)sB[q] * 64 + lane];
            }
            if (!pref) {  // prefetch next-chunk meta under the first gathers
                pref = true;
                if (lane < 32) {
                    if (c0 + 32 + lane < en0) pn = packed[c0 + 32 + lane];
                } else {
                    if (c1 + lane < en1) pn = packed[c1 + lane];
                }
            }
            float dA[8], dB[8];
#pragma unroll
            for (int q = 0; q < 8; ++q) {
                dA[q] = __shfl(d, j + q);
                dB[q] = __shfl(d, 32 + j + q);
            }
#pragma unroll
            for (int q = 0; q < 8; ++q) {
                a0 = fmaf(dA[q], bflo(uA[q]), a0);
                a1 = fmaf(dA[q], bfhi(uA[q]), a1);
                b0 = fmaf(dB[q], bflo(uB[q]), b0);
                b1 = fmaf(dB[q], bfhi(uB[q]), b1);
            }
        }
        p = pn;
    }

    float2 bb = ((const float2*)bias)[lane];
    a0 = fmaf(a0, dv0, bb.x);
    a1 = fmaf(a1, dv0, bb.y);
    b0 = fmaf(b0, dv1, bb.x);
    b1 = fmaf(b1, dv1, bb.y);
    if (RELU) {
        a0 = fmaxf(a0, 0.f);
        a1 = fmaxf(a1, 0.f);
        b0 = fmaxf(b0, 0.f);
        b1 = fmaxf(b1, 0.f);
    }
    Xb[(size_t)v0 * 64 + lane] = bf16pack(a0, a1);
    if (h1) Xb[(size_t)v1 * 64 + lane] = bf16pack(b0, b1);
}

// ---------------- edge scoring: 4 label edges per wave (bias pre-folded) ----
__global__ __launch_bounds__(256) void score_kernel(const int* __restrict__ ea,
                                                    const int* __restrict__ eb,
                                                    const unsigned int* __restrict__ Xb,
                                                    float* __restrict__ out) {
    int wbase = (blockIdx.x * 4 + (threadIdx.x >> 6)) * 4;
    int lane = threadIdx.x & 63;
    if (wbase >= N_LABEL) return;
    int ne = N_LABEL - wbase;
    if (ne > 4) ne = 4;

    unsigned int ua[4], ub[4];
#pragma unroll
    for (int e = 0; e < 4; ++e)
        if (e < ne) {
            int ia = ea[wbase + e], ib = eb[wbase + e];
            ua[e] = Xb[(size_t)ia * 64 + lane];
            ub[e] = Xb[(size_t)ib * 64 + lane];
        }
#pragma unroll
    for (int e = 0; e < 4; ++e)
        if (e < ne) {
            float p = bflo(ua[e]) * bflo(ub[e]) + bfhi(ua[e]) * bfhi(ub[e]);
#pragma unroll
            for (int off = 32; off > 0; off >>= 1) p += __shfl_down(p, off);
            if (lane == 0) out[wbase + e] = p;
        }
}

extern "C" void kernel_launch(void* const* d_in, const int* in_sizes, int n_in,
                              void* d_out, int out_size, void* d_ws, size_t ws_size,
                              hipStream_t stream) {
    const float* feat = (const float*)d_in[0];
    const int* ei = (const int*)d_in[1];
    const int* eli = (const int*)d_in[2];
    const float* W1 = (const float*)d_in[3];
    const float* b1 = (const float*)d_in[4];
    const float* W2 = (const float*)d_in[5];
    const float* b2 = (const float*)d_in[6];
    float* out = (float*)d_out;

    const int* src = ei;
    const int* dst = ei + N_EDGES;
    const int* la = eli;
    const int* lb = eli + N_LABEL;

    int* row_ptr = (int*)d_ws;                                // N+4 ints
    float* dinv = (float*)(row_ptr + N_NODES + 4);            // N
    unsigned short* wt1 = (unsigned short*)(dinv + N_NODES);  // 16384 ushort
    unsigned short* wt2 = wt1 + 16384;                        // 16384 ushort
    int* packed = (int*)(wt2 + 16384);                        // E ints (4 MB)
    unsigned int* Hb = (unsigned int*)(packed + N_EDGES);     // N*64 uints
    unsigned int* Xb = Hb + (size_t)N_NODES * 64;             // N*64 uints
    // temp (block-major records, 4 MB) + bofs (245*783 ints) alias Xb
    unsigned int* temp = Xb;
    int* bofs = (int*)(temp + (size_t)P1_BLOCKS * 4096);

    const int TB = 256;
    int gGemm = (N_NODES + BM - 1) / BM;  // 782
    int gAgg = (N_NODES + 7) / 8;         // 12500
    int gScore = (N_LABEL + 15) / 16;     // 12500

    // launch0: W conversion (no gcur/memset needed anymore)
    w2bf<<<G_CONV, TB, 0, stream>>>(W1, W2, wt1, wt2);

    // gemm1 || pass1 (pass1 now scatter-free: pure streaming)
    fused_gemm1_pass1<<<G_GEMM + P1_BLOCKS, TB, 0, stream>>>(
        feat, wt1, Hb, src, dst, temp, bofs);

    // CSR fine sort (segment gather from L3-hot temp)
    pass2_sort<<<NB, TB, 0, stream>>>(temp, bofs, row_ptr, dinv, packed);

    // layer 1 aggregate
    aggregate<true><<<gAgg, TB, 0, stream>>>(Hb, packed, row_ptr, dinv, b1, Xb);

    // layer 2
    gemm128_mfma_bf16<<<gGemm, TB, 0, stream>>>(Xb, wt2, Hb, N_NODES);
    aggregate<false><<<gAgg, TB, 0, stream>>>(Hb, packed, row_ptr, dinv, b2, Xb);

    // scoring (b2 already folded into Xb)
    score_kernel<<<gScore, TB, 0, stream>>>(la, lb, Xb, out);
}

// Round 8
// 275.815 us; speedup vs baseline: 1.0985x; 1.0095x over previous
//
#include <hip/hip_runtime.h>
#include <hip/hip_bf16.h>

// GCN link-prediction: 2x GCNConv(128->128) + edge dot scoring.
// Round 20: launch-count cut + overlap re-pairing. Accounting vs counters
// shows ~30-40us of inter-launch gaps (7 dispatches, ~3-5us each; R18's
// memset removal = -3us confirms). Legal re-pairing by dependency:
//   L0 = {w2bf || pass1}   (both depend on nothing)
//   L1 = {gemm1 || pass2}  (gemm1 needs only wt1; pass2 needs only pass1)
// -> 6 launches, pass2 hidden under gemm1 again (R19 left it serial).
// gemm_body/aggregate/score byte-identical to R19 (proven).
// LESSONS BANKED:
// - aggregate gather: pinned at ~3.65 TB/s random-64B fabric floor; FETCH
//   181MB invariant; issue-order micro-tuning is noise (R17).
// - never fuse latency-bound gather with reg/LDS-heavy MFMA (R10).
// - never read MFMA B-frags strided from global - INCLUDING LDS staging
//   reads; pre-convert W coalesced (R11, R16: +20us).
// - partial-line scatter = write-allocate amplification (R13, R18).
// - CSR via LDS counting sort >> 1M global atomics (R14: -57us).
// - launch gap ~3-5us each: minimize dispatch count (R18/R19 accounting).

#define N_NODES 100000
#define N_EDGES 1000000
#define N_LABEL 200000
#define D_FEAT 128
#define BM 128

#define NB 782        // coarse buckets: ceil(100000/128) nodes each
#define BCAP 2048     // pass2 LDS capacity per bucket (mean 1279, +6sig ~1500)
#define P1_EPT 16     // pass1 edges per thread
#define P1_BLOCKS 245 // ceil(1e6/4096)
#define G_GEMM 782    // ceil(100000/128)
#define G_CONV 128    // W1+W2 conversion blocks (32768 elems / 256)

typedef short bf16x8 __attribute__((ext_vector_type(8)));
typedef float f32x4 __attribute__((ext_vector_type(4)));

// ---- bf16 helpers (RNE) ----
__device__ inline unsigned int f2bf(float x) {
    unsigned int u = __float_as_uint(x);
    return (u + 0x7FFFu + ((u >> 16) & 1u)) >> 16;
}
__device__ inline unsigned int bf16pack(float a, float b) {
    return f2bf(a) | (f2bf(b) << 16);
}
__device__ inline float bflo(unsigned int u) { return __uint_as_float(u << 16); }
__device__ inline float bfhi(unsigned int u) { return __uint_as_float(u & 0xFFFF0000u); }

// ---------------- L0: {w2bf || pass1 (scatter-free)} ------------------------
// blocks [0,G_CONV): W->bf16 transpose. blocks [G_CONV, G_CONV+P1_BLOCKS):
// pass1 block b sorts its 4096 edges by bucket in LDS, dumps block-major
// temp[b*4096] coalesced + bofs[b][0..782]. No global atomics.
__global__ __launch_bounds__(256) void w2bf_pass1(
    const float* __restrict__ W1, const float* __restrict__ W2,
    unsigned short* __restrict__ Wt1, unsigned short* __restrict__ Wt2,
    const int* __restrict__ src, const int* __restrict__ dst,
    unsigned int* __restrict__ temp, int* __restrict__ bofs) {
    __shared__ __align__(16) unsigned int S[4096 + 1024 + 256];  // 21.5 KB
    int b = blockIdx.x, t = threadIdx.x;
    if (b < G_CONV) {
        int i = b * 256 + t;  // 0..32767
        const float* W = (i < 16384) ? W1 : W2;
        unsigned short* Wt = (i < 16384) ? Wt1 : Wt2;
        int j = i & 16383;
        int n = j >> 7, k = j & 127;
        Wt[j] = (unsigned short)f2bf(W[(size_t)k * 128 + n]);
        return;
    }
    b -= G_CONV;
    unsigned int* ed16 = S;            // 4096 u32 (16 KB)
    int* hist = (int*)(ed16 + 4096);   // 1024 ints (bins padded)
    int* red = hist + 1024;            // 256

    for (int i = t; i < 1024; i += 256) hist[i] = 0;
    __syncthreads();

    int se[P1_EPT], de[P1_EPT], rk[P1_EPT];
    int e0 = b * 4096 + t;
#pragma unroll
    for (int j = 0; j < P1_EPT; ++j) {
        int e = e0 + j * 256;
        if (e < N_EDGES) {
            se[j] = src[e];
            de[j] = dst[e];
            rk[j] = atomicAdd(&hist[de[j] >> 7], 1);
        }
    }
    __syncthreads();

    // exclusive scan over 1024 bins: thread t owns bins 4t..4t+3
    int c0 = hist[4 * t], c1 = hist[4 * t + 1], c2 = hist[4 * t + 2], c3 = hist[4 * t + 3];
    int s = c0 + c1 + c2 + c3;
    red[t] = s;
    __syncthreads();
    for (int off = 1; off < 256; off <<= 1) {
        int a = (t >= off) ? red[t - off] : 0;
        __syncthreads();
        red[t] += a;
        __syncthreads();
    }
    int excl = red[t] - s;
    hist[4 * t] = excl;
    hist[4 * t + 1] = excl + c0;
    hist[4 * t + 2] = excl + c0 + c1;
    hist[4 * t + 3] = excl + c0 + c1 + c2;
    __syncthreads();

    // scatter records into LDS (bucket-sorted within block)
#pragma unroll
    for (int j = 0; j < P1_EPT; ++j) {
        int e = e0 + j * 256;
        if (e < N_EDGES) {
            int pos = hist[de[j] >> 7] + rk[j];
            ed16[pos] = (unsigned int)(((de[j] & 127) << 17) | se[j]);
        }
    }
    __syncthreads();

    // coalesced dump + bofs
#pragma unroll
    for (int i = 0; i < 4; ++i)
        ((uint4*)temp)[(size_t)b * 1024 + i * 256 + t] = ((uint4*)ed16)[i * 256 + t];
    for (int j = t; j < NB; j += 256) bofs[b * (NB + 1) + j] = hist[j];
    if (t == 0) {
        int cnt = N_EDGES - b * 4096;
        if (cnt > 4096) cnt = 4096;
        bofs[b * (NB + 1) + NB] = cnt;
    }
}

// ---------------- MFMA GEMM body, LDS-staged bf16 W ----------------
template <bool BF16_IN>
__device__ __forceinline__ void gemm_body(const void* __restrict__ Xv,
                                          const unsigned short* __restrict__ Wt,
                                          unsigned int* __restrict__ Y,
                                          int nrows, int bid, short* Ws) {
    int t = threadIdx.x;
#pragma unroll
    for (int i = 0; i < 8; ++i) {
        int c = i * 256 + t;
        int n = c >> 4, q = c & 15;
        uint4 v = *(const uint4*)&Wt[(size_t)n * 128 + q * 8];
        *(uint4*)&Ws[n * 128 + ((q ^ (n & 15)) << 3)] = v;
    }
    __syncthreads();

    int wv = t >> 6;
    int lane = t & 63, l16 = lane & 15, quad = lane >> 4;
    int rbase = bid * BM + wv * 32;

    f32x4 acc[2][8];
#pragma unroll
    for (int rt = 0; rt < 2; ++rt)
#pragma unroll
        for (int nt = 0; nt < 8; ++nt) acc[rt][nt] = (f32x4){0.f, 0.f, 0.f, 0.f};

#pragma unroll
    for (int kb = 0; kb < 4; ++kb) {
        bf16x8 af[2];
#pragma unroll
        for (int rt = 0; rt < 2; ++rt) {
            int row = rbase + rt * 16 + l16;
            if (row > nrows - 1) row = nrows - 1;
            if constexpr (BF16_IN) {
                const unsigned int* Xb = (const unsigned int*)Xv;
                af[rt] = *(const bf16x8*)&Xb[(size_t)row * 64 + kb * 16 + quad * 4];
            } else {
                const float* X = (const float*)Xv;
                float4 fa = ((const float4*)X)[(size_t)row * 32 + kb * 8 + quad * 2];
                float4 fb = ((const float4*)X)[(size_t)row * 32 + kb * 8 + quad * 2 + 1];
                union { uint4 u; bf16x8 v; } cv;
                cv.u.x = bf16pack(fa.x, fa.y);
                cv.u.y = bf16pack(fa.z, fa.w);
                cv.u.z = bf16pack(fb.x, fb.y);
                cv.u.w = bf16pack(fb.z, fb.w);
                af[rt] = cv.v;
            }
        }
        bf16x8 bfr[8];
#pragma unroll
        for (int nt = 0; nt < 8; ++nt) {
            int n = nt * 16 + l16;
            bfr[nt] = *(const bf16x8*)&Ws[n * 128 + (((kb * 4 + quad) ^ l16) << 3)];
        }
#pragma unroll
        for (int rt = 0; rt < 2; ++rt)
#pragma unroll
            for (int nt = 0; nt < 8; ++nt)
                acc[rt][nt] = __builtin_amdgcn_mfma_f32_16x16x32_bf16(
                    af[rt], bfr[nt], acc[rt][nt], 0, 0, 0);
    }

    short* Ys = (short*)Y;
#pragma unroll
    for (int rt = 0; rt < 2; ++rt)
#pragma unroll
        for (int reg = 0; reg < 4; ++reg) {
            int row = rbase + rt * 16 + quad * 4 + reg;
            if (row < nrows) {
#pragma unroll
                for (int nt = 0; nt < 8; ++nt)
                    Ys[(size_t)row * 128 + nt * 16 + l16] = (short)f2bf(acc[rt][nt][reg]);
            }
        }
}

// standalone GEMM (layer 2, bf16 input)
__global__ __launch_bounds__(256) void gemm128_mfma_bf16(const unsigned int* __restrict__ Xb,
                                                         const unsigned short* __restrict__ Wt,
                                                         unsigned int* __restrict__ Y,
                                                         int nrows) {
    __shared__ __align__(16) short Ws[128 * 128];
    gemm_body<true>(Xb, Wt, Y, nrows, blockIdx.x, Ws);
}

// ---------------- L1: {gemm1 (f32 input) || pass2 fine sort} ----------------
// pass2 block k: gather its 245 segments from block-major temp (L2/L3-hot),
// gbase = sum_b bofs[b][k], LDS fine counting sort, contiguous packed write.
// pass2's ~12.5KB lives inside gemm's 32KB Ws union.
__global__ __launch_bounds__(256) void fused_gemm1_pass2(
    const float* __restrict__ feat, const unsigned short* __restrict__ wt1,
    unsigned int* __restrict__ Hb,
    const unsigned int* __restrict__ temp, const int* __restrict__ bofs,
    int* __restrict__ row_ptr, float* __restrict__ dinv,
    int* __restrict__ packed) {
    __shared__ __align__(16) short Ws[128 * 128];  // gemm tile / pass2 union
    int b = blockIdx.x, t = threadIdx.x;
    if (b < G_GEMM) {
        gemm_body<false>(feat, wt1, Hb, N_NODES, b, Ws);
        return;
    }
    int k = b - G_GEMM;
    unsigned int* ed = (unsigned int*)Ws;  // BCAP u32 (8 KB)
    int* hist = (int*)(ed + BCAP);         // 128
    int* rp = hist + 128;                  // 128
    int* cur = rp + 128;                   // 128
    int* sc2 = cur + 128;                  // 128
    int* red = sc2 + 128;                  // 256
    int* sc = red + 256;                   // 256

    int s_t = 0, len = 0;
    if (t < P1_BLOCKS) {
        s_t = bofs[t * (NB + 1) + k];
        len = bofs[t * (NB + 1) + k + 1] - s_t;
    }
    // gbase = sum_b s_b
    red[t] = s_t;
    __syncthreads();
    for (int off = 128; off > 0; off >>= 1) {
        if (t < off) red[t] += red[t + off];
        __syncthreads();
    }
    int gbase = red[0];
    __syncthreads();
    // dloc: exclusive scan of segment lengths
    sc[t] = len;
    __syncthreads();
    for (int off = 1; off < 256; off <<= 1) {
        int a = (t >= off) ? sc[t - off] : 0;
        __syncthreads();
        sc[t] += a;
        __syncthreads();
    }
    int dloc = sc[t] - len;
    int nk = sc[255];
    if (nk > BCAP) nk = BCAP;

    if (t < 128) { hist[t] = 0; cur[t] = 0; }
    __syncthreads();
    // gather segments into LDS
    for (int i = 0; i < len; ++i) {
        int d = dloc + i;
        if (d < BCAP) ed[d] = temp[(size_t)t * 4096 + s_t + i];
    }
    __syncthreads();
    for (int i = t; i < nk; i += 256) atomicAdd(&hist[ed[i] >> 17], 1);
    __syncthreads();

    // exclusive scan over 128 bins
    if (t < 128) sc2[t] = hist[t];
    __syncthreads();
    for (int off = 1; off < 128; off <<= 1) {
        int a = (t < 128 && t >= off) ? sc2[t - off] : 0;
        __syncthreads();
        if (t < 128) sc2[t] += a;
        __syncthreads();
    }
    if (t < 128) {
        rp[t] = sc2[t] - hist[t];
        int n = k * 128 + t;
        if (n < N_NODES) {
            row_ptr[n] = gbase + rp[t];
            dinv[n] = rsqrtf((float)(hist[t] + 1));  // +1 self-loop
        }
    }
    if (k == NB - 1 && t == 0) row_ptr[N_NODES] = N_EDGES;
    __syncthreads();

    for (int i = t; i < nk; i += 256) {
        unsigned int v = ed[i];
        int dl = v >> 17;
        int r = atomicAdd(&cur[dl], 1);
        packed[gbase + rp[dl] + r] = (int)(v & 0x1FFFF);
    }
}

// ---------------- gather-aggregate: 2 nodes/wave, 16 gathers in flight ----
// packed = src only (4B/edge). x[v] = dv*(dv*H[v] + sum_s dinv[s]*H[s]) + b.
template <bool RELU>
__global__ __launch_bounds__(256) void aggregate(const unsigned int* __restrict__ Hb,
                                                 const int* __restrict__ packed,
                                                 const int* __restrict__ row_ptr,
                                                 const float* __restrict__ dinv,
                                                 const float* __restrict__ bias,
                                                 unsigned int* __restrict__ Xb) {
    int v0 = blockIdx.x * 8 + (threadIdx.x >> 6) * 2;
    int v1 = v0 + 1;
    int lane = threadIdx.x & 63;
    if (v0 >= N_NODES) return;
    bool h1 = (v1 < N_NODES);

    int st0 = row_ptr[v0], en0 = row_ptr[v0 + 1];
    int st1 = h1 ? row_ptr[v1] : 0, en1 = h1 ? row_ptr[v1 + 1] : 0;
    float dv0 = dinv[v0];
    float dv1 = h1 ? dinv[v1] : 0.f;

    unsigned int su0 = Hb[(size_t)v0 * 64 + lane];
    float a0 = dv0 * bflo(su0), a1 = dv0 * bfhi(su0);
    unsigned int su1 = h1 ? Hb[(size_t)v1 * 64 + lane] : 0u;
    float b0 = dv1 * bflo(su1), b1 = dv1 * bfhi(su1);

    // meta prefetch for first chunk
    int p = 0;
    if (lane < 32) {
        if (st0 + lane < en0) p = packed[st0 + lane];
    } else {
        if (st1 + lane - 32 < en1) p = packed[st1 + lane - 32];
    }

    for (int c0 = st0, c1 = st1; c0 < en0 || c1 < en1; c0 += 32, c1 += 32) {
        int n0 = en0 - c0; n0 = n0 < 0 ? 0 : (n0 > 32 ? 32 : n0);
        int n1 = en1 - c1; n1 = n1 < 0 ? 0 : (n1 > 32 ? 32 : n1);
        bool act = (lane < 32) ? (lane < n0) : (lane - 32 < n1);
        float dld = dinv[p];          // p=0 for inactive lanes: safe addr
        float d = act ? dld : 0.f;    // masked after load

        int nmax = n0 > n1 ? n0 : n1;
        int pn = 0;
        bool pref = false;
        for (int j = 0; j < nmax; j += 8) {
            int sA[8], sB[8];
#pragma unroll
            for (int q = 0; q < 8; ++q) {
                sA[q] = __shfl(p, j + q);
                sB[q] = __shfl(p, 32 + j + q);
            }
            unsigned int uA[8], uB[8];
#pragma unroll
            for (int q = 0; q < 8; ++q) {
                uA[q] = Hb[(size_t)sA[q] * 64 + lane];
                uB[q] = Hb[(size_t)sB[q] * 64 + lane];
            }
            if (!pref) {  // prefetch next-chunk meta under the first gathers
                pref = true;
                if (lane < 32) {
                    if (c0 + 32 + lane < en0) pn = packed[c0 + 32 + lane];
                } else {
                    if (c1 + lane < en1) pn = packed[c1 + lane];
                }
            }
            float dA[8], dB[8];
#pragma unroll
            for (int q = 0; q < 8; ++q) {
                dA[q] = __shfl(d, j + q);
                dB[q] = __shfl(d, 32 + j + q);
            }
#pragma unroll
            for (int q = 0; q < 8; ++q) {
                a0 = fmaf(dA[q], bflo(uA[q]), a0);
                a1 = fmaf(dA[q], bfhi(uA[q]), a1);
                b0 = fmaf(dB[q], bflo(uB[q]), b0);
                b1 = fmaf(dB[q], bfhi(uB[q]), b1);
            }
        }
        p = pn;
    }

    float2 bb = ((const float2*)bias)[lane];
    a0 = fmaf(a0, dv0, bb.x);
    a1 = fmaf(a1, dv0, bb.y);
    b0 = fmaf(b0, dv1, bb.x);
    b1 = fmaf(b1, dv1, bb.y);
    if (RELU) {
        a0 = fmaxf(a0, 0.f);
        a1 = fmaxf(a1, 0.f);
        b0 = fmaxf(b0, 0.f);
        b1 = fmaxf(b1, 0.f);
    }
    Xb[(size_t)v0 * 64 + lane] = bf16pack(a0, a1);
    if (h1) Xb[(size_t)v1 * 64 + lane] = bf16pack(b0, b1);
}

// ---------------- edge scoring: 4 label edges per wave (bias pre-folded) ----
__global__ __launch_bounds__(256) void score_kernel(const int* __restrict__ ea,
                                                    const int* __restrict__ eb,
                                                    const unsigned int* __restrict__ Xb,
                                                    float* __restrict__ out) {
    int wbase = (blockIdx.x * 4 + (threadIdx.x >> 6)) * 4;
    int lane = threadIdx.x & 63;
    if (wbase >= N_LABEL) return;
    int ne = N_LABEL - wbase;
    if (ne > 4) ne = 4;

    unsigned int ua[4], ub[4];
#pragma unroll
    for (int e = 0; e < 4; ++e)
        if (e < ne) {
            int ia = ea[wbase + e], ib = eb[wbase + e];
            ua[e] = Xb[(size_t)ia * 64 + lane];
            ub[e] = Xb[(size_t)ib * 64 + lane];
        }
#pragma unroll
    for (int e = 0; e < 4; ++e)
        if (e < ne) {
            float p = bflo(ua[e]) * bflo(ub[e]) + bfhi(ua[e]) * bfhi(ub[e]);
#pragma unroll
            for (int off = 32; off > 0; off >>= 1) p += __shfl_down(p, off);
            if (lane == 0) out[wbase + e] = p;
        }
}

extern "C" void kernel_launch(void* const* d_in, const int* in_sizes, int n_in,
                              void* d_out, int out_size, void* d_ws, size_t ws_size,
                              hipStream_t stream) {
    const float* feat = (const float*)d_in[0];
    const int* ei = (const int*)d_in[1];
    const int* eli = (const int*)d_in[2];
    const float* W1 = (const float*)d_in[3];
    const float* b1 = (const float*)d_in[4];
    const float* W2 = (const float*)d_in[5];
    const float* b2 = (const float*)d_in[6];
    float* out = (float*)d_out;

    const int* src = ei;
    const int* dst = ei + N_EDGES;
    const int* la = eli;
    const int* lb = eli + N_LABEL;

    int* row_ptr = (int*)d_ws;                                // N+4 ints
    float* dinv = (float*)(row_ptr + N_NODES + 4);            // N
    unsigned short* wt1 = (unsigned short*)(dinv + N_NODES);  // 16384 ushort
    unsigned short* wt2 = wt1 + 16384;                        // 16384 ushort
    int* packed = (int*)(wt2 + 16384);                        // E ints (4 MB)
    unsigned int* Hb = (unsigned int*)(packed + N_EDGES);     // N*64 uints
    unsigned int* Xb = Hb + (size_t)N_NODES * 64;             // N*64 uints
    // temp (block-major records, 4 MB) + bofs (245*783 ints) alias Xb
    unsigned int* temp = Xb;
    int* bofs = (int*)(temp + (size_t)P1_BLOCKS * 4096);

    const int TB = 256;
    int gGemm = (N_NODES + BM - 1) / BM;  // 782
    int gAgg = (N_NODES + 7) / 8;         // 12500
    int gScore = (N_LABEL + 15) / 16;     // 12500

    // L0: w2bf || pass1 (both independent of everything)
    w2bf_pass1<<<G_CONV + P1_BLOCKS, TB, 0, stream>>>(W1, W2, wt1, wt2,
                                                      src, dst, temp, bofs);

    // L1: gemm1 || pass2 (gemm1 needs wt1 only; pass2 needs pass1 only)
    fused_gemm1_pass2<<<G_GEMM + NB, TB, 0, stream>>>(
        feat, wt1, Hb, temp, bofs, row_ptr, dinv, packed);

    // layer 1 aggregate
    aggregate<true><<<gAgg, TB, 0, stream>>>(Hb, packed, row_ptr, dinv, b1, Xb);

    // layer 2
    gemm128_mfma_bf16<<<gGemm, TB, 0, stream>>>(Xb, wt2, Hb, N_NODES);
    aggregate<false><<<gAgg, TB, 0, stream>>>(Hb, packed, row_ptr, dinv, b2, Xb);

    // scoring (b2 already folded into Xb)
    score_kernel<<<gScore, TB, 0, stream>>>(la, lb, Xb, out);
}